// Round 14
// baseline (84.303 us; speedup 1.0000x reference)
//
#include <hip/hip_runtime.h>
#include <hip/hip_bf16.h>

typedef short short8 __attribute__((ext_vector_type(8)));
typedef float f32x4 __attribute__((ext_vector_type(4)));
typedef float f32x16 __attribute__((ext_vector_type(16)));
typedef int int4v __attribute__((ext_vector_type(4)));
typedef unsigned short ushort4v __attribute__((ext_vector_type(4)));

#define NB 4
#define NS 4096
#define NE 128
#define ALPHA 0.1275174468f  /* log2(e)/sqrt(128) */
#define KVB 64                 /* keys per tile */
#define NIT (NS / KVB)         /* 64 */
#define SPLITS 4               /* 16-key splits */
#define DEFER_THR 8.0f         /* log2 units: P bounded by 2^8 */

static __device__ __forceinline__ unsigned short f2bf(float f) {
  union { float f; unsigned int u; } v; v.f = f;
  unsigned int u = v.u;
  return (unsigned short)((u + 0x7FFFu + ((u >> 16) & 1u)) >> 16);
}
static __device__ __forceinline__ unsigned int pack2bf(float a, float b) {
  union { __hip_bfloat162 h; unsigned int u; } v;
  v.h = __float22bfloat162_rn(float2{a, b});
  return v.u;
}
static __device__ __forceinline__ short8 as_s8(int4v x) {
  union { int4v i; short8 s; } u; u.i = x; return u.s;
}

// ---------------------------------------------------------------------------
// Staged ws layouts (per batch, per 64-key tile, 16 groups x 1KB, contiguous):
//  K group jt*4+ks, lane=gg*16+li: K[j=jt*16+li][e=ks*32+gg*8+..7]
//  V group sp*4+et, lane=hi*32+l31: V[j=sp*16+hi*8+..7][e=et*32+l31]
// ---------------------------------------------------------------------------

__global__ __launch_bounds__(256) void prep_k(
    const float* __restrict__ Wq, const float* __restrict__ Wk,
    const float* __restrict__ Wv,
    unsigned short* __restrict__ Wqb, unsigned short* __restrict__ Wkb,
    unsigned short* __restrict__ Wvb) {
  int i = blockIdx.x * 256 + threadIdx.x;
  const float* srcs[3] = {Wq, Wk, Wv};
  unsigned short* dsts[3] = {Wqb, Wkb, Wvb};
  int m = i >> 12, off = (i & 4095) * 4;
  float4 v = *(const float4*)(srcs[m] + off);
  ushort4v o;
  o[0] = f2bf(v.x); o[1] = f2bf(v.y); o[2] = f2bf(v.z); o[3] = f2bf(v.w);
  *(ushort4v*)(dsts[m] + off) = o;
}

static __device__ __forceinline__ f32x4 wtile(const short8 xa[4],
                                              const unsigned short* __restrict__ Wb,
                                              int fb, int g, int li) {
  f32x4 acc = {0.f, 0.f, 0.f, 0.f};
  #pragma unroll
  for (int ks = 0; ks < 4; ++ks) {
    short8 wf = *(const short8*)(Wb + (fb * 16 + li) * NE + ks * 32 + g * 8);
    acc = __builtin_amdgcn_mfma_f32_16x16x32_bf16(xa[ks], wf, acc, 0, 0, 0);
  }
  return acc;
}

// ---------------------------------------------------------------------------
// Kernel 1: fused QKV projection (f32 in; Q row-major, K/V staged layout).
// ---------------------------------------------------------------------------
__global__ __launch_bounds__(256) void qkv_proj_k(
    const float* __restrict__ X,
    const unsigned short* __restrict__ Wqb, const float* __restrict__ bq,
    const unsigned short* __restrict__ Wkb, const float* __restrict__ bk,
    const unsigned short* __restrict__ Wvb, const float* __restrict__ bv,
    unsigned short* __restrict__ Qs, unsigned short* __restrict__ Kd,
    unsigned short* __restrict__ VT) {
  const int lane = threadIdx.x & 63;
  const int wv   = threadIdx.x >> 6;
  const int tile = (blockIdx.x >> 1) * 4 + wv;   // 0..1023
  const int fb0  = (blockIdx.x & 1) * 4;         // output half
  const int m0   = tile * 16;
  const int g    = lane >> 4, li = lane & 15;

  short8 xa[4];
  #pragma unroll
  for (int ks = 0; ks < 4; ++ks) {
    const float* xp = X + (size_t)(m0 + li) * NE + ks * 32 + g * 8;
    float4 x0 = *(const float4*)xp;
    float4 x1 = *(const float4*)(xp + 4);
    short8 t;
    t[0] = (short)f2bf(x0.x); t[1] = (short)f2bf(x0.y);
    t[2] = (short)f2bf(x0.z); t[3] = (short)f2bf(x0.w);
    t[4] = (short)f2bf(x1.x); t[5] = (short)f2bf(x1.y);
    t[6] = (short)f2bf(x1.z); t[7] = (short)f2bf(x1.w);
    xa[ks] = t;
  }

  const int bb  = m0 >> 12;              // batch
  const int tT  = (m0 & 4095) >> 6;      // 64-key tile within batch
  const int jtT = (m0 >> 4) & 3;         // 16-key subtile (= sp)
  const size_t tgbase = ((size_t)(bb * 64 + tT)) * 16;   // group base (x512)

  #pragma unroll
  for (int f2 = 0; f2 < 4; ++f2) {
    const int fb = fb0 + f2;
    // ---- Q ----
    f32x4 aq = wtile(xa, Wqb, fb, g, li);
    float biq = bq[fb * 16 + li];
    #pragma unroll
    for (int r = 0; r < 4; ++r)
      Qs[(size_t)(m0 + g * 4 + r) * NE + fb * 16 + li] = f2bf((aq[r] + biq) * ALPHA);
    // ---- K staged ----
    f32x4 ak = wtile(xa, Wkb, fb, g, li);
    float bik = bk[fb * 16 + li];
    unsigned short* kdst = Kd + (tgbase + jtT * 4 + (fb >> 1)) * 512 +
                           ((fb & 1) * 2 + (li >> 3)) * 128 + (li & 7);
    #pragma unroll
    for (int r = 0; r < 4; ++r)
      kdst[(g * 4 + r) * 8] = f2bf(ak[r] + bik);
    // ---- V staged (wave-major group = jtT*4 + (fb>>1)) ----
    f32x4 av = wtile(xa, Wvb, fb, g, li);
    float biv = bv[fb * 16 + li];
    ushort4v pv;
    #pragma unroll
    for (int r = 0; r < 4; ++r) pv[r] = f2bf(av[r] + biv);
    *(ushort4v*)(VT + (tgbase + jtT * 4 + (fb >> 1)) * 512 +
                 ((g >> 1) * 32 + (fb & 1) * 16 + li) * 8 + (g & 1) * 4) = pv;
  }
}

// ---------------------------------------------------------------------------
// Kernel 2: flash attention. 256 blocks x 512 threads = 1 block/CU,
// 8 waves/CU. Block = 64 q-rows (2 q-groups x 32) x 4 key-splits -> each
// K/V byte read from L2 serves 64 q-rows (2x round-13) => L2 traffic halves
// (was at the ~35 TB/s L2 ceiling). Per-wave inner loop identical to r13:
// reg-double-buffered asm global loads, counted vmcnt(8), defer-max.
// ---------------------------------------------------------------------------
__global__ __launch_bounds__(512, 2) void attn_k(
    const unsigned short* __restrict__ Qs, const unsigned short* __restrict__ Kd,
    const unsigned short* __restrict__ VT, float* __restrict__ Out) {
  __shared__ float smO[2 * SPLITS * 4 * 64 * 16];   // 128 KB
  __shared__ float smML[2 * SPLITS * 64];           // 2 KB

  const int lane = threadIdx.x & 63;
  const int wv   = threadIdx.x >> 6;             // 0..7
  const int qg   = wv >> 2;                      // q-group (0..1)
  const int sp   = wv & 3;                       // key split (0..3)
  const int bi   = blockIdx.x;                   // 0..255
  const int b    = (bi >> 1) & 3;                // batch tied to XCD pair
  const int within = ((bi >> 3) << 1) | (bi & 1);     // 0..63
  const int qb   = within * 64 + qg * 32;        // q-row base for this wave
  const int g    = lane >> 4, li = lane & 15;
  const int l31  = lane & 31, hi = lane >> 5;
  const bool qsel = (lane >> 4) & 1;

  // ---- Q B-frags via asm loads ----
  int4v q00, q01, q02, q03, q10, q11, q12, q13;
  {
    const unsigned short* q0 = Qs + (size_t)(b * NS + qb + li) * NE + g * 8;
    const unsigned short* q1 = Qs + (size_t)(b * NS + qb + 16 + li) * NE + g * 8;
    unsigned long long a0 = (unsigned long long)q0, a1 = (unsigned long long)q1;
    asm volatile("global_load_dwordx4 %0, %1, off"             : "=v"(q00) : "v"(a0));
    asm volatile("global_load_dwordx4 %0, %1, off offset:64"   : "=v"(q01) : "v"(a0));
    asm volatile("global_load_dwordx4 %0, %1, off offset:128"  : "=v"(q02) : "v"(a0));
    asm volatile("global_load_dwordx4 %0, %1, off offset:192"  : "=v"(q03) : "v"(a0));
    asm volatile("global_load_dwordx4 %0, %1, off"             : "=v"(q10) : "v"(a1));
    asm volatile("global_load_dwordx4 %0, %1, off offset:64"   : "=v"(q11) : "v"(a1));
    asm volatile("global_load_dwordx4 %0, %1, off offset:128"  : "=v"(q12) : "v"(a1));
    asm volatile("global_load_dwordx4 %0, %1, off offset:192"  : "=v"(q13) : "v"(a1));
  }

  const size_t stbase = (size_t)b * 64 * 16 * 512;       // shorts
  const int    kvoff  = sp * 2048 + lane * 8;            // shorts
  const unsigned long long kbase =
      (unsigned long long)(Kd + stbase + kvoff);
  const unsigned long long vbase =
      (unsigned long long)(VT + stbase + kvoff);

  int4v ka0, ka1, ka2, ka3, va0, va1, va2, va3;
  int4v kb0, kb1, kb2, kb3, vb0, vb1, vb2, vb3;

  #define LOAD_SET(K0,K1,K2,K3,V0,V1,V2,V3,T)                                   \
    {                                                                           \
      unsigned long long ka_ = kbase + (unsigned long long)(T) * 16384;         \
      unsigned long long va_ = vbase + (unsigned long long)(T) * 16384;         \
      asm volatile("global_load_dwordx4 %0, %1, off"             : "=v"(K0) : "v"(ka_)); \
      asm volatile("global_load_dwordx4 %0, %1, off offset:1024" : "=v"(K1) : "v"(ka_)); \
      asm volatile("global_load_dwordx4 %0, %1, off offset:2048" : "=v"(K2) : "v"(ka_)); \
      asm volatile("global_load_dwordx4 %0, %1, off offset:3072" : "=v"(K3) : "v"(ka_)); \
      asm volatile("global_load_dwordx4 %0, %1, off"             : "=v"(V0) : "v"(va_)); \
      asm volatile("global_load_dwordx4 %0, %1, off offset:1024" : "=v"(V1) : "v"(va_)); \
      asm volatile("global_load_dwordx4 %0, %1, off offset:2048" : "=v"(V2) : "v"(va_)); \
      asm volatile("global_load_dwordx4 %0, %1, off offset:3072" : "=v"(V3) : "v"(va_)); \
    }
  #define LOAD_A(T) LOAD_SET(ka0,ka1,ka2,ka3,va0,va1,va2,va3,T)
  #define LOAD_B(T) LOAD_SET(kb0,kb1,kb2,kb3,vb0,vb1,vb2,vb3,T)
  #define WAIT8 asm volatile("s_waitcnt vmcnt(8)" ::: "memory"); \
                __builtin_amdgcn_sched_barrier(0);

  f32x16 o[4];
  #pragma unroll
  for (int et = 0; et < 4; ++et)
    #pragma unroll
    for (int r = 0; r < 16; ++r) o[et][r] = 0.f;
  float m0 = -1e30f, m1 = -1e30f, L0 = 0.f, L1 = 0.f;

  const int src01 = (lane & 15) | (lane & 32);
  const int src23 = src01 + 16;

  #define BODY(K0,K1,K2,K3,V0,V1,V2,V3)                                        \
  {                                                                            \
    f32x4 s0 = {0.f, 0.f, 0.f, 0.f}, s1 = {0.f, 0.f, 0.f, 0.f};                \
    __builtin_amdgcn_s_setprio(1);                                             \
    s0 = __builtin_amdgcn_mfma_f32_16x16x32_bf16(as_s8(K0), as_s8(q00), s0, 0,0,0); \
    s1 = __builtin_amdgcn_mfma_f32_16x16x32_bf16(as_s8(K0), as_s8(q10), s1, 0,0,0); \
    s0 = __builtin_amdgcn_mfma_f32_16x16x32_bf16(as_s8(K1), as_s8(q01), s0, 0,0,0); \
    s1 = __builtin_amdgcn_mfma_f32_16x16x32_bf16(as_s8(K1), as_s8(q11), s1, 0,0,0); \
    s0 = __builtin_amdgcn_mfma_f32_16x16x32_bf16(as_s8(K2), as_s8(q02), s0, 0,0,0); \
    s1 = __builtin_amdgcn_mfma_f32_16x16x32_bf16(as_s8(K2), as_s8(q12), s1, 0,0,0); \
    s0 = __builtin_amdgcn_mfma_f32_16x16x32_bf16(as_s8(K3), as_s8(q03), s0, 0,0,0); \
    s1 = __builtin_amdgcn_mfma_f32_16x16x32_bf16(as_s8(K3), as_s8(q13), s1, 0,0,0); \
    __builtin_amdgcn_s_setprio(0);                                             \
    float tm0 = fmaxf(fmaxf(s0[0], s0[1]), fmaxf(s0[2], s0[3]));               \
    float tm1 = fmaxf(fmaxf(s1[0], s1[1]), fmaxf(s1[2], s1[3]));               \
    if (__any(fmaxf(tm0 - m0, tm1 - m1) > DEFER_THR)) {                        \
      tm0 = fmaxf(tm0, __shfl_xor(tm0, 16));                                   \
      tm1 = fmaxf(tm1, __shfl_xor(tm1, 16));                                   \
      tm0 = fmaxf(tm0, __shfl_xor(tm0, 32));                                   \
      tm1 = fmaxf(tm1, __shfl_xor(tm1, 32));                                   \
      float mn0 = fmaxf(m0, tm0), c0 = __builtin_amdgcn_exp2f(m0 - mn0);       \
      float mn1 = fmaxf(m1, tm1), c1 = __builtin_amdgcn_exp2f(m1 - mn1);       \
      const float cmy = qsel ? c1 : c0;                                        \
      o[0] = o[0] * cmy; o[1] = o[1] * cmy;                                    \
      o[2] = o[2] * cmy; o[3] = o[3] * cmy;                                    \
      L0 *= c0; L1 *= c1; m0 = mn0; m1 = mn1;                                  \
    }                                                                          \
    float p00 = __builtin_amdgcn_exp2f(s0[0] - m0);                            \
    float p01 = __builtin_amdgcn_exp2f(s0[1] - m0);                            \
    float p02 = __builtin_amdgcn_exp2f(s0[2] - m0);                            \
    float p03 = __builtin_amdgcn_exp2f(s0[3] - m0);                            \
    float p10 = __builtin_amdgcn_exp2f(s1[0] - m1);                            \
    float p11 = __builtin_amdgcn_exp2f(s1[1] - m1);                            \
    float p12 = __builtin_amdgcn_exp2f(s1[2] - m1);                            \
    float p13 = __builtin_amdgcn_exp2f(s1[3] - m1);                            \
    L0 += (p00 + p01) + (p02 + p03);                                           \
    L1 += (p10 + p11) + (p12 + p13);                                           \
    unsigned int pk00 = pack2bf(p00, p01);                                     \
    unsigned int pk01 = pack2bf(p02, p03);                                     \
    unsigned int pk10 = pack2bf(p10, p11);                                     \
    unsigned int pk11 = pack2bf(p12, p13);                                     \
    int ta, tb, w0, w1, w2, w3;                                                \
    ta = __shfl((int)pk00, src01); tb = __shfl((int)pk10, src01);              \
    w0 = qsel ? tb : ta;                                                       \
    ta = __shfl((int)pk01, src01); tb = __shfl((int)pk11, src01);              \
    w1 = qsel ? tb : ta;                                                       \
    ta = __shfl((int)pk00, src23); tb = __shfl((int)pk10, src23);              \
    w2 = qsel ? tb : ta;                                                       \
    ta = __shfl((int)pk01, src23); tb = __shfl((int)pk11, src23);              \
    w3 = qsel ? tb : ta;                                                       \
    union { int4v i4; short8 s8; } pb;                                         \
    pb.i4 = (int4v){w0, w1, w2, w3};                                           \
    __builtin_amdgcn_s_setprio(1);                                             \
    o[0] = __builtin_amdgcn_mfma_f32_32x32x16_bf16(as_s8(V0), pb.s8, o[0], 0,0,0); \
    o[1] = __builtin_amdgcn_mfma_f32_32x32x16_bf16(as_s8(V1), pb.s8, o[1], 0,0,0); \
    o[2] = __builtin_amdgcn_mfma_f32_32x32x16_bf16(as_s8(V2), pb.s8, o[2], 0,0,0); \
    o[3] = __builtin_amdgcn_mfma_f32_32x32x16_bf16(as_s8(V3), pb.s8, o[3], 0,0,0); \
    __builtin_amdgcn_s_setprio(0);                                             \
  }

  LOAD_A(0);
  WAIT8;   // Q frags ready; tile 0 in flight

  #pragma unroll 1
  for (int t2 = 0; t2 < NIT; t2 += 2) {
    LOAD_B(t2 + 1);
    WAIT8;
    BODY(ka0, ka1, ka2, ka3, va0, va1, va2, va3)
    LOAD_A((t2 + 2) & (NIT - 1));
    WAIT8;
    BODY(kb0, kb1, kb2, kb3, vb0, vb1, vb2, vb3)
  }

  __syncthreads();

  // ---- epilogue: publish split partials ([qg][sp][et][lane][16]) ----
  L0 += __shfl_xor(L0, 16); L0 += __shfl_xor(L0, 32);
  L1 += __shfl_xor(L1, 16); L1 += __shfl_xor(L1, 32);
  #pragma unroll
  for (int et = 0; et < 4; ++et)
    #pragma unroll
    for (int rq = 0; rq < 4; ++rq) {
      float4 v;
      v.x = o[et][rq * 4 + 0]; v.y = o[et][rq * 4 + 1];
      v.z = o[et][rq * 4 + 2]; v.w = o[et][rq * 4 + 3];
      *(float4*)(smO + (size_t)(((qg * SPLITS + sp) * 4 + et) * 64 + lane) * 16 + rq * 4) = v;
    }
  if (lane < 16) {
    smML[(qg * SPLITS + sp) * 64 + lane]      = m0;
    smML[(qg * SPLITS + sp) * 64 + 16 + lane] = m1;
    smML[(qg * SPLITS + sp) * 64 + 32 + lane] = L0;
    smML[(qg * SPLITS + sp) * 64 + 48 + lane] = L1;
  }
  __syncthreads();

  // ---- combine: wave wv handles (q-group wv>>2, e-block wv&3) ----
  const int cqg = wv >> 2, cet = wv & 3;
  float ms[SPLITS], Ls[SPLITS];
  #pragma unroll
  for (int sp2 = 0; sp2 < SPLITS; ++sp2) {
    ms[sp2] = smML[(cqg * SPLITS + sp2) * 64 + l31];
    Ls[sp2] = smML[(cqg * SPLITS + sp2) * 64 + 32 + l31];
  }
  float M = fmaxf(fmaxf(ms[0], ms[1]), fmaxf(ms[2], ms[3]));
  float W[SPLITS], Ltot = 0.f;
  #pragma unroll
  for (int sp2 = 0; sp2 < SPLITS; ++sp2) {
    W[sp2] = __builtin_amdgcn_exp2f(ms[sp2] - M);
    Ltot += W[sp2] * Ls[sp2];
  }
  const float rL = 1.f / Ltot;
  float* Orow = Out + (size_t)(b * NS + within * 64 + cqg * 32 + l31) * NE + cet * 32;
  #pragma unroll
  for (int rq = 0; rq < 4; ++rq) {
    float4 acc = make_float4(0.f, 0.f, 0.f, 0.f);
    #pragma unroll
    for (int sp2 = 0; sp2 < SPLITS; ++sp2) {
      float4 v = *(const float4*)(smO +
          (size_t)(((cqg * SPLITS + sp2) * 4 + cet) * 64 + lane) * 16 + rq * 4);
      acc.x += W[sp2] * v.x; acc.y += W[sp2] * v.y;
      acc.z += W[sp2] * v.z; acc.w += W[sp2] * v.w;
    }
    acc.x *= rL; acc.y *= rL; acc.z *= rL; acc.w *= rL;
    *(float4*)(Orow + 8 * rq + 4 * hi) = acc;
  }
}

extern "C" void kernel_launch(void* const* d_in, const int* in_sizes, int n_in,
                              void* d_out, int out_size, void* d_ws, size_t ws_size,
                              hipStream_t stream) {
  const float* X  = (const float*)d_in[0];
  // d_in[1] = context : unused (per-row bias is softmax-invariant)
  const float* Wq = (const float*)d_in[2];
  const float* bq = (const float*)d_in[3];
  const float* Wk = (const float*)d_in[4];
  const float* bk = (const float*)d_in[5];
  const float* Wv = (const float*)d_in[6];
  const float* bv = (const float*)d_in[7];
  // d_in[8] = Wc, d_in[9] = bc : unused

  unsigned short* Qs  = (unsigned short*)d_ws;                // 4 MB
  unsigned short* Kd  = Qs + (size_t)NB * NS * NE;            // 4 MB (staged)
  unsigned short* VT  = Kd + (size_t)NB * NS * NE;            // 4 MB (staged)
  unsigned short* Wqb = VT + (size_t)NB * NS * NE;            // 32 KB x3
  unsigned short* Wkb = Wqb + NE * NE;
  unsigned short* Wvb = Wkb + NE * NE;

  prep_k<<<48, 256, 0, stream>>>(Wq, Wk, Wv, Wqb, Wkb, Wvb);
  qkv_proj_k<<<512, 256, 0, stream>>>(X, Wqb, bq, Wkb, bk, Wvb, bv, Qs, Kd, VT);
  attn_k<<<256, 512, 0, stream>>>(Qs, Kd, VT, (float*)d_out);
}

// Round 17
// 81.786 us; speedup vs baseline: 1.0308x; 1.0308x over previous
//
#include <hip/hip_runtime.h>
#include <hip/hip_bf16.h>

typedef short short8 __attribute__((ext_vector_type(8)));
typedef float f32x4 __attribute__((ext_vector_type(4)));
typedef float f32x16 __attribute__((ext_vector_type(16)));
typedef int int4v __attribute__((ext_vector_type(4)));
typedef unsigned short ushort4v __attribute__((ext_vector_type(4)));

#define NB 4
#define NS 4096
#define NE 128
#define ALPHA 0.1275174468f  /* log2(e)/sqrt(128) */
#define KVB 64                 /* keys per tile */
#define NIT (NS / KVB)         /* 64 */
#define SPLITS 4               /* 16-key splits */
#define DEFER_THR 8.0f         /* log2 units: P bounded by 2^8 */

static __device__ __forceinline__ unsigned short f2bf(float f) {
  union { float f; unsigned int u; } v; v.f = f;
  unsigned int u = v.u;
  return (unsigned short)((u + 0x7FFFu + ((u >> 16) & 1u)) >> 16);
}
static __device__ __forceinline__ unsigned int pack2bf(float a, float b) {
  union { __hip_bfloat162 h; unsigned int u; } v;
  v.h = __float22bfloat162_rn(float2{a, b});
  return v.u;
}
static __device__ __forceinline__ short8 as_s8(int4v x) {
  union { int4v i; short8 s; } u; u.i = x; return u.s;
}

// ---------------------------------------------------------------------------
// Staged ws layouts (per batch, per 64-key tile, 16 groups x 1KB, contiguous):
//  K group jt*4+ks, lane=gg*16+li: K[j=jt*16+li][e=ks*32+gg*8+..7]
//  V group sp*4+et, lane=hi*32+l31: V[j=sp*16+hi*8+..7][e=et*32+l31]
// ---------------------------------------------------------------------------

__global__ __launch_bounds__(256) void prep_k(
    const float* __restrict__ Wq, const float* __restrict__ Wk,
    const float* __restrict__ Wv,
    unsigned short* __restrict__ Wqb, unsigned short* __restrict__ Wkb,
    unsigned short* __restrict__ Wvb) {
  int i = blockIdx.x * 256 + threadIdx.x;
  const float* srcs[3] = {Wq, Wk, Wv};
  unsigned short* dsts[3] = {Wqb, Wkb, Wvb};
  int m = i >> 12, off = (i & 4095) * 4;
  float4 v = *(const float4*)(srcs[m] + off);
  ushort4v o;
  o[0] = f2bf(v.x); o[1] = f2bf(v.y); o[2] = f2bf(v.z); o[3] = f2bf(v.w);
  *(ushort4v*)(dsts[m] + off) = o;
}

static __device__ __forceinline__ f32x4 wtile(const short8 xa[4],
                                              const unsigned short* __restrict__ Wb,
                                              int fb, int g, int li) {
  f32x4 acc = {0.f, 0.f, 0.f, 0.f};
  #pragma unroll
  for (int ks = 0; ks < 4; ++ks) {
    short8 wf = *(const short8*)(Wb + (fb * 16 + li) * NE + ks * 32 + g * 8);
    acc = __builtin_amdgcn_mfma_f32_16x16x32_bf16(xa[ks], wf, acc, 0, 0, 0);
  }
  return acc;
}

// ---------------------------------------------------------------------------
// Kernel 1: fused QKV projection. Grid 1024: 2 fb-slices per block ->
// 4 blocks/CU, 16 waves/CU (was 2 blocks/CU, parallelism-starved).
// ---------------------------------------------------------------------------
__global__ __launch_bounds__(256, 4) void qkv_proj_k(
    const float* __restrict__ X,
    const unsigned short* __restrict__ Wqb, const float* __restrict__ bq,
    const unsigned short* __restrict__ Wkb, const float* __restrict__ bk,
    const unsigned short* __restrict__ Wvb, const float* __restrict__ bv,
    unsigned short* __restrict__ Qs, unsigned short* __restrict__ Kd,
    unsigned short* __restrict__ VT) {
  const int lane = threadIdx.x & 63;
  const int wv   = threadIdx.x >> 6;
  const int tile = (blockIdx.x >> 2) * 4 + wv;   // 0..1023
  const int fb0  = (blockIdx.x & 3) * 2;         // output slice (2 fb)
  const int m0   = tile * 16;
  const int g    = lane >> 4, li = lane & 15;

  short8 xa[4];
  #pragma unroll
  for (int ks = 0; ks < 4; ++ks) {
    const float* xp = X + (size_t)(m0 + li) * NE + ks * 32 + g * 8;
    float4 x0 = *(const float4*)xp;
    float4 x1 = *(const float4*)(xp + 4);
    short8 t;
    t[0] = (short)f2bf(x0.x); t[1] = (short)f2bf(x0.y);
    t[2] = (short)f2bf(x0.z); t[3] = (short)f2bf(x0.w);
    t[4] = (short)f2bf(x1.x); t[5] = (short)f2bf(x1.y);
    t[6] = (short)f2bf(x1.z); t[7] = (short)f2bf(x1.w);
    xa[ks] = t;
  }

  const int bb  = m0 >> 12;              // batch
  const int tT  = (m0 & 4095) >> 6;      // 64-key tile within batch
  const int jtT = (m0 >> 4) & 3;         // 16-key subtile (= sp)
  const size_t tgbase = ((size_t)(bb * 64 + tT)) * 16;   // group base (x512)

  #pragma unroll
  for (int f2 = 0; f2 < 2; ++f2) {
    const int fb = fb0 + f2;
    // ---- Q ----
    f32x4 aq = wtile(xa, Wqb, fb, g, li);
    float biq = bq[fb * 16 + li];
    #pragma unroll
    for (int r = 0; r < 4; ++r)
      Qs[(size_t)(m0 + g * 4 + r) * NE + fb * 16 + li] = f2bf((aq[r] + biq) * ALPHA);
    // ---- K staged ----
    f32x4 ak = wtile(xa, Wkb, fb, g, li);
    float bik = bk[fb * 16 + li];
    unsigned short* kdst = Kd + (tgbase + jtT * 4 + (fb >> 1)) * 512 +
                           ((fb & 1) * 2 + (li >> 3)) * 128 + (li & 7);
    #pragma unroll
    for (int r = 0; r < 4; ++r)
      kdst[(g * 4 + r) * 8] = f2bf(ak[r] + bik);
    // ---- V staged (wave-major group = jtT*4 + (fb>>1)) ----
    f32x4 av = wtile(xa, Wvb, fb, g, li);
    float biv = bv[fb * 16 + li];
    ushort4v pv;
    #pragma unroll
    for (int r = 0; r < 4; ++r) pv[r] = f2bf(av[r] + biv);
    *(ushort4v*)(VT + (tgbase + jtT * 4 + (fb >> 1)) * 512 +
                 ((g >> 1) * 32 + (fb & 1) * 16 + li) * 8 + (g & 1) * 4) = pv;
  }
}

// ---------------------------------------------------------------------------
// Kernel 2: flash attention — BYTE-IDENTICAL to the round-14 passing source.
// 256 blocks x 512 threads, 8 waves/CU. Block = 64 q-rows x 4 key-splits.
// Reg-double-buffered asm global loads, counted vmcnt(8), defer-max.
// ---------------------------------------------------------------------------
__global__ __launch_bounds__(512, 2) void attn_k(
    const unsigned short* __restrict__ Qs, const unsigned short* __restrict__ Kd,
    const unsigned short* __restrict__ VT, float* __restrict__ Out) {
  __shared__ float smO[2 * SPLITS * 4 * 64 * 16];   // 128 KB
  __shared__ float smML[2 * SPLITS * 64];           // 2 KB

  const int lane = threadIdx.x & 63;
  const int wv   = threadIdx.x >> 6;             // 0..7
  const int qg   = wv >> 2;                      // q-group (0..1)
  const int sp   = wv & 3;                       // key split (0..3)
  const int bi   = blockIdx.x;                   // 0..255
  const int b    = (bi >> 1) & 3;                // batch tied to XCD pair
  const int within = ((bi >> 3) << 1) | (bi & 1);     // 0..63
  const int qb   = within * 64 + qg * 32;        // q-row base for this wave
  const int g    = lane >> 4, li = lane & 15;
  const int l31  = lane & 31, hi = lane >> 5;
  const bool qsel = (lane >> 4) & 1;

  // ---- Q B-frags via asm loads ----
  int4v q00, q01, q02, q03, q10, q11, q12, q13;
  {
    const unsigned short* q0 = Qs + (size_t)(b * NS + qb + li) * NE + g * 8;
    const unsigned short* q1 = Qs + (size_t)(b * NS + qb + 16 + li) * NE + g * 8;
    unsigned long long a0 = (unsigned long long)q0, a1 = (unsigned long long)q1;
    asm volatile("global_load_dwordx4 %0, %1, off"             : "=v"(q00) : "v"(a0));
    asm volatile("global_load_dwordx4 %0, %1, off offset:64"   : "=v"(q01) : "v"(a0));
    asm volatile("global_load_dwordx4 %0, %1, off offset:128"  : "=v"(q02) : "v"(a0));
    asm volatile("global_load_dwordx4 %0, %1, off offset:192"  : "=v"(q03) : "v"(a0));
    asm volatile("global_load_dwordx4 %0, %1, off"             : "=v"(q10) : "v"(a1));
    asm volatile("global_load_dwordx4 %0, %1, off offset:64"   : "=v"(q11) : "v"(a1));
    asm volatile("global_load_dwordx4 %0, %1, off offset:128"  : "=v"(q12) : "v"(a1));
    asm volatile("global_load_dwordx4 %0, %1, off offset:192"  : "=v"(q13) : "v"(a1));
  }

  const size_t stbase = (size_t)b * 64 * 16 * 512;       // shorts
  const int    kvoff  = sp * 2048 + lane * 8;            // shorts
  const unsigned long long kbase =
      (unsigned long long)(Kd + stbase + kvoff);
  const unsigned long long vbase =
      (unsigned long long)(VT + stbase + kvoff);

  int4v ka0, ka1, ka2, ka3, va0, va1, va2, va3;
  int4v kb0, kb1, kb2, kb3, vb0, vb1, vb2, vb3;

  #define LOAD_SET(K0,K1,K2,K3,V0,V1,V2,V3,T)                                   \
    {                                                                           \
      unsigned long long ka_ = kbase + (unsigned long long)(T) * 16384;         \
      unsigned long long va_ = vbase + (unsigned long long)(T) * 16384;         \
      asm volatile("global_load_dwordx4 %0, %1, off"             : "=v"(K0) : "v"(ka_)); \
      asm volatile("global_load_dwordx4 %0, %1, off offset:1024" : "=v"(K1) : "v"(ka_)); \
      asm volatile("global_load_dwordx4 %0, %1, off offset:2048" : "=v"(K2) : "v"(ka_)); \
      asm volatile("global_load_dwordx4 %0, %1, off offset:3072" : "=v"(K3) : "v"(ka_)); \
      asm volatile("global_load_dwordx4 %0, %1, off"             : "=v"(V0) : "v"(va_)); \
      asm volatile("global_load_dwordx4 %0, %1, off offset:1024" : "=v"(V1) : "v"(va_)); \
      asm volatile("global_load_dwordx4 %0, %1, off offset:2048" : "=v"(V2) : "v"(va_)); \
      asm volatile("global_load_dwordx4 %0, %1, off offset:3072" : "=v"(V3) : "v"(va_)); \
    }
  #define LOAD_A(T) LOAD_SET(ka0,ka1,ka2,ka3,va0,va1,va2,va3,T)
  #define LOAD_B(T) LOAD_SET(kb0,kb1,kb2,kb3,vb0,vb1,vb2,vb3,T)
  #define WAIT8 asm volatile("s_waitcnt vmcnt(8)" ::: "memory"); \
                __builtin_amdgcn_sched_barrier(0);

  f32x16 o[4];
  #pragma unroll
  for (int et = 0; et < 4; ++et)
    #pragma unroll
    for (int r = 0; r < 16; ++r) o[et][r] = 0.f;
  float m0 = -1e30f, m1 = -1e30f, L0 = 0.f, L1 = 0.f;

  const int src01 = (lane & 15) | (lane & 32);
  const int src23 = src01 + 16;

  #define BODY(K0,K1,K2,K3,V0,V1,V2,V3)                                        \
  {                                                                            \
    f32x4 s0 = {0.f, 0.f, 0.f, 0.f}, s1 = {0.f, 0.f, 0.f, 0.f};                \
    __builtin_amdgcn_s_setprio(1);                                             \
    s0 = __builtin_amdgcn_mfma_f32_16x16x32_bf16(as_s8(K0), as_s8(q00), s0, 0,0,0); \
    s1 = __builtin_amdgcn_mfma_f32_16x16x32_bf16(as_s8(K0), as_s8(q10), s1, 0,0,0); \
    s0 = __builtin_amdgcn_mfma_f32_16x16x32_bf16(as_s8(K1), as_s8(q01), s0, 0,0,0); \
    s1 = __builtin_amdgcn_mfma_f32_16x16x32_bf16(as_s8(K1), as_s8(q11), s1, 0,0,0); \
    s0 = __builtin_amdgcn_mfma_f32_16x16x32_bf16(as_s8(K2), as_s8(q02), s0, 0,0,0); \
    s1 = __builtin_amdgcn_mfma_f32_16x16x32_bf16(as_s8(K2), as_s8(q12), s1, 0,0,0); \
    s0 = __builtin_amdgcn_mfma_f32_16x16x32_bf16(as_s8(K3), as_s8(q03), s0, 0,0,0); \
    s1 = __builtin_amdgcn_mfma_f32_16x16x32_bf16(as_s8(K3), as_s8(q13), s1, 0,0,0); \
    __builtin_amdgcn_s_setprio(0);                                             \
    float tm0 = fmaxf(fmaxf(s0[0], s0[1]), fmaxf(s0[2], s0[3]));               \
    float tm1 = fmaxf(fmaxf(s1[0], s1[1]), fmaxf(s1[2], s1[3]));               \
    if (__any(fmaxf(tm0 - m0, tm1 - m1) > DEFER_THR)) {                        \
      tm0 = fmaxf(tm0, __shfl_xor(tm0, 16));                                   \
      tm1 = fmaxf(tm1, __shfl_xor(tm1, 16));                                   \
      tm0 = fmaxf(tm0, __shfl_xor(tm0, 32));                                   \
      tm1 = fmaxf(tm1, __shfl_xor(tm1, 32));                                   \
      float mn0 = fmaxf(m0, tm0), c0 = __builtin_amdgcn_exp2f(m0 - mn0);       \
      float mn1 = fmaxf(m1, tm1), c1 = __builtin_amdgcn_exp2f(m1 - mn1);       \
      const float cmy = qsel ? c1 : c0;                                        \
      o[0] = o[0] * cmy; o[1] = o[1] * cmy;                                    \
      o[2] = o[2] * cmy; o[3] = o[3] * cmy;                                    \
      L0 *= c0; L1 *= c1; m0 = mn0; m1 = mn1;                                  \
    }                                                                          \
    float p00 = __builtin_amdgcn_exp2f(s0[0] - m0);                            \
    float p01 = __builtin_amdgcn_exp2f(s0[1] - m0);                            \
    float p02 = __builtin_amdgcn_exp2f(s0[2] - m0);                            \
    float p03 = __builtin_amdgcn_exp2f(s0[3] - m0);                            \
    float p10 = __builtin_amdgcn_exp2f(s1[0] - m1);                            \
    float p11 = __builtin_amdgcn_exp2f(s1[1] - m1);                            \
    float p12 = __builtin_amdgcn_exp2f(s1[2] - m1);                            \
    float p13 = __builtin_amdgcn_exp2f(s1[3] - m1);                            \
    L0 += (p00 + p01) + (p02 + p03);                                           \
    L1 += (p10 + p11) + (p12 + p13);                                           \
    unsigned int pk00 = pack2bf(p00, p01);                                     \
    unsigned int pk01 = pack2bf(p02, p03);                                     \
    unsigned int pk10 = pack2bf(p10, p11);                                     \
    unsigned int pk11 = pack2bf(p12, p13);                                     \
    int ta, tb, w0, w1, w2, w3;                                                \
    ta = __shfl((int)pk00, src01); tb = __shfl((int)pk10, src01);              \
    w0 = qsel ? tb : ta;                                                       \
    ta = __shfl((int)pk01, src01); tb = __shfl((int)pk11, src01);              \
    w1 = qsel ? tb : ta;                                                       \
    ta = __shfl((int)pk00, src23); tb = __shfl((int)pk10, src23);              \
    w2 = qsel ? tb : ta;                                                       \
    ta = __shfl((int)pk01, src23); tb = __shfl((int)pk11, src23);              \
    w3 = qsel ? tb : ta;                                                       \
    union { int4v i4; short8 s8; } pb;                                         \
    pb.i4 = (int4v){w0, w1, w2, w3};                                           \
    __builtin_amdgcn_s_setprio(1);                                             \
    o[0] = __builtin_amdgcn_mfma_f32_32x32x16_bf16(as_s8(V0), pb.s8, o[0], 0,0,0); \
    o[1] = __builtin_amdgcn_mfma_f32_32x32x16_bf16(as_s8(V1), pb.s8, o[1], 0,0,0); \
    o[2] = __builtin_amdgcn_mfma_f32_32x32x16_bf16(as_s8(V2), pb.s8, o[2], 0,0,0); \
    o[3] = __builtin_amdgcn_mfma_f32_32x32x16_bf16(as_s8(V3), pb.s8, o[3], 0,0,0); \
    __builtin_amdgcn_s_setprio(0);                                             \
  }

  LOAD_A(0);
  WAIT8;   // Q frags ready; tile 0 in flight

  #pragma unroll 1
  for (int t2 = 0; t2 < NIT; t2 += 2) {
    LOAD_B(t2 + 1);
    WAIT8;
    BODY(ka0, ka1, ka2, ka3, va0, va1, va2, va3)
    LOAD_A((t2 + 2) & (NIT - 1));
    WAIT8;
    BODY(kb0, kb1, kb2, kb3, vb0, vb1, vb2, vb3)
  }

  __syncthreads();

  // ---- epilogue: publish split partials ([qg][sp][et][lane][16]) ----
  L0 += __shfl_xor(L0, 16); L0 += __shfl_xor(L0, 32);
  L1 += __shfl_xor(L1, 16); L1 += __shfl_xor(L1, 32);
  #pragma unroll
  for (int et = 0; et < 4; ++et)
    #pragma unroll
    for (int rq = 0; rq < 4; ++rq) {
      float4 v;
      v.x = o[et][rq * 4 + 0]; v.y = o[et][rq * 4 + 1];
      v.z = o[et][rq * 4 + 2]; v.w = o[et][rq * 4 + 3];
      *(float4*)(smO + (size_t)(((qg * SPLITS + sp) * 4 + et) * 64 + lane) * 16 + rq * 4) = v;
    }
  if (lane < 16) {
    smML[(qg * SPLITS + sp) * 64 + lane]      = m0;
    smML[(qg * SPLITS + sp) * 64 + 16 + lane] = m1;
    smML[(qg * SPLITS + sp) * 64 + 32 + lane] = L0;
    smML[(qg * SPLITS + sp) * 64 + 48 + lane] = L1;
  }
  __syncthreads();

  // ---- combine: wave wv handles (q-group wv>>2, e-block wv&3) ----
  const int cqg = wv >> 2, cet = wv & 3;
  float ms[SPLITS], Ls[SPLITS];
  #pragma unroll
  for (int sp2 = 0; sp2 < SPLITS; ++sp2) {
    ms[sp2] = smML[(cqg * SPLITS + sp2) * 64 + l31];
    Ls[sp2] = smML[(cqg * SPLITS + sp2) * 64 + 32 + l31];
  }
  float M = fmaxf(fmaxf(ms[0], ms[1]), fmaxf(ms[2], ms[3]));
  float W[SPLITS], Ltot = 0.f;
  #pragma unroll
  for (int sp2 = 0; sp2 < SPLITS; ++sp2) {
    W[sp2] = __builtin_amdgcn_exp2f(ms[sp2] - M);
    Ltot += W[sp2] * Ls[sp2];
  }
  const float rL = 1.f / Ltot;
  float* Orow = Out + (size_t)(b * NS + within * 64 + cqg * 32 + l31) * NE + cet * 32;
  #pragma unroll
  for (int rq = 0; rq < 4; ++rq) {
    float4 acc = make_float4(0.f, 0.f, 0.f, 0.f);
    #pragma unroll
    for (int sp2 = 0; sp2 < SPLITS; ++sp2) {
      float4 v = *(const float4*)(smO +
          (size_t)(((cqg * SPLITS + sp2) * 4 + cet) * 64 + lane) * 16 + rq * 4);
      acc.x += W[sp2] * v.x; acc.y += W[sp2] * v.y;
      acc.z += W[sp2] * v.z; acc.w += W[sp2] * v.w;
    }
    acc.x *= rL; acc.y *= rL; acc.z *= rL; acc.w *= rL;
    *(float4*)(Orow + 8 * rq + 4 * hi) = acc;
  }
}

extern "C" void kernel_launch(void* const* d_in, const int* in_sizes, int n_in,
                              void* d_out, int out_size, void* d_ws, size_t ws_size,
                              hipStream_t stream) {
  const float* X  = (const float*)d_in[0];
  // d_in[1] = context : unused (per-row bias is softmax-invariant)
  const float* Wq = (const float*)d_in[2];
  const float* bq = (const float*)d_in[3];
  const float* Wk = (const float*)d_in[4];
  const float* bk = (const float*)d_in[5];
  const float* Wv = (const float*)d_in[6];
  const float* bv = (const float*)d_in[7];
  // d_in[8] = Wc, d_in[9] = bc : unused

  unsigned short* Qs  = (unsigned short*)d_ws;                // 4 MB
  unsigned short* Kd  = Qs + (size_t)NB * NS * NE;            // 4 MB (staged)
  unsigned short* VT  = Kd + (size_t)NB * NS * NE;            // 4 MB (staged)
  unsigned short* Wqb = VT + (size_t)NB * NS * NE;            // 32 KB x3
  unsigned short* Wkb = Wqb + NE * NE;
  unsigned short* Wvb = Wkb + NE * NE;

  prep_k<<<48, 256, 0, stream>>>(Wq, Wk, Wv, Wqb, Wkb, Wvb);
  qkv_proj_k<<<1024, 256, 0, stream>>>(X, Wqb, bq, Wkb, bk, Wvb, bv, Qs, Kd, VT);
  attn_k<<<256, 512, 0, stream>>>(Qs, Kd, VT, (float*)d_out);
}

// Round 18
// 81.073 us; speedup vs baseline: 1.0398x; 1.0088x over previous
//
#include <hip/hip_runtime.h>
#include <hip/hip_bf16.h>

typedef short short8 __attribute__((ext_vector_type(8)));
typedef float f32x4 __attribute__((ext_vector_type(4)));
typedef float f32x16 __attribute__((ext_vector_type(16)));
typedef int int4v __attribute__((ext_vector_type(4)));
typedef unsigned short ushort4v __attribute__((ext_vector_type(4)));

#define NB 4
#define NS 4096
#define NE 128
#define ALPHA 0.1275174468f  /* log2(e)/sqrt(128) */
#define KVB 64                 /* keys per tile */
#define NIT (NS / KVB)         /* 64 */
#define SPLITS 4               /* 16-key splits */
#define DEFER_THR 8.0f         /* log2 units: P bounded by 2^8 */

static __device__ __forceinline__ unsigned short f2bf(float f) {
  union { float f; unsigned int u; } v; v.f = f;
  unsigned int u = v.u;
  return (unsigned short)((u + 0x7FFFu + ((u >> 16) & 1u)) >> 16);
}
static __device__ __forceinline__ unsigned int pack2bf(float a, float b) {
  union { __hip_bfloat162 h; unsigned int u; } v;
  v.h = __float22bfloat162_rn(float2{a, b});
  return v.u;
}
static __device__ __forceinline__ short8 as_s8(int4v x) {
  union { int4v i; short8 s; } u; u.i = x; return u.s;
}

// ---------------------------------------------------------------------------
// Staged ws layouts (per batch, per 64-key tile, 16 groups x 1KB, contiguous):
//  K group jt*4+ks, lane=gg*16+li: K[j=jt*16+li][e=ks*32+gg*8+..7]
//  V group sp*4+et, lane=hi*32+l31: V[j=sp*16+hi*8+..7][e=et*32+l31]
// ---------------------------------------------------------------------------

__global__ __launch_bounds__(256) void prep_k(
    const float* __restrict__ Wq, const float* __restrict__ Wk,
    const float* __restrict__ Wv,
    unsigned short* __restrict__ Wqb, unsigned short* __restrict__ Wkb,
    unsigned short* __restrict__ Wvb) {
  int i = blockIdx.x * 256 + threadIdx.x;
  const float* srcs[3] = {Wq, Wk, Wv};
  unsigned short* dsts[3] = {Wqb, Wkb, Wvb};
  int m = i >> 12, off = (i & 4095) * 4;
  float4 v = *(const float4*)(srcs[m] + off);
  ushort4v o;
  o[0] = f2bf(v.x); o[1] = f2bf(v.y); o[2] = f2bf(v.z); o[3] = f2bf(v.w);
  *(ushort4v*)(dsts[m] + off) = o;
}

static __device__ __forceinline__ f32x4 wtile(const short8 xa[4],
                                              const unsigned short* __restrict__ Wb,
                                              int fb, int g, int li) {
  f32x4 acc = {0.f, 0.f, 0.f, 0.f};
  #pragma unroll
  for (int ks = 0; ks < 4; ++ks) {
    short8 wf = *(const short8*)(Wb + (fb * 16 + li) * NE + ks * 32 + g * 8);
    acc = __builtin_amdgcn_mfma_f32_16x16x32_bf16(xa[ks], wf, acc, 0, 0, 0);
  }
  return acc;
}

// ---------------------------------------------------------------------------
// Kernel 1: fused QKV projection. Grid 1024, 2 fb-slices per block.
// Q/K fragments bounce through a wave-private 1KB LDS tile (scalar ds_write,
// linear ds_read_b128) so EVERY global store is a coalesced 16B burst --
// the old 2B scalar stores at 256B stride were ~64 cache lines per wave
// instruction and dominated qkv time. Staged ws bytes are bit-identical.
// ---------------------------------------------------------------------------
__global__ __launch_bounds__(256, 4) void qkv_proj_k(
    const float* __restrict__ X,
    const unsigned short* __restrict__ Wqb, const float* __restrict__ bq,
    const unsigned short* __restrict__ Wkb, const float* __restrict__ bk,
    const unsigned short* __restrict__ Wvb, const float* __restrict__ bv,
    unsigned short* __restrict__ Qs, unsigned short* __restrict__ Kd,
    unsigned short* __restrict__ VT) {
  __shared__ __align__(16) unsigned short qt[4][512];   // per-wave 1KB tiles
  __shared__ __align__(16) unsigned short kt[4][512];

  const int lane = threadIdx.x & 63;
  const int wv   = threadIdx.x >> 6;
  const int tile = (blockIdx.x >> 2) * 4 + wv;   // 0..1023
  const int fb0  = (blockIdx.x & 3) * 2;         // output slice (2 fb, even)
  const int m0   = tile * 16;
  const int g    = lane >> 4, li = lane & 15;

  short8 xa[4];
  #pragma unroll
  for (int ks = 0; ks < 4; ++ks) {
    const float* xp = X + (size_t)(m0 + li) * NE + ks * 32 + g * 8;
    float4 x0 = *(const float4*)xp;
    float4 x1 = *(const float4*)(xp + 4);
    short8 t;
    t[0] = (short)f2bf(x0.x); t[1] = (short)f2bf(x0.y);
    t[2] = (short)f2bf(x0.z); t[3] = (short)f2bf(x0.w);
    t[4] = (short)f2bf(x1.x); t[5] = (short)f2bf(x1.y);
    t[6] = (short)f2bf(x1.z); t[7] = (short)f2bf(x1.w);
    xa[ks] = t;
  }

  const int bb  = m0 >> 12;              // batch
  const int tT  = (m0 & 4095) >> 6;      // 64-key tile within batch
  const int jtT = (m0 >> 4) & 3;         // 16-key subtile (= sp)
  const size_t tgbase = ((size_t)(bb * 64 + tT)) * 16;   // group base (x512)

  #pragma unroll
  for (int f2 = 0; f2 < 2; ++f2) {
    const int fb = fb0 + f2;
    // ---- Q -> LDS tile, row-major [j 16][e' 32] ----
    f32x4 aq = wtile(xa, Wqb, fb, g, li);
    float biq = bq[fb * 16 + li];
    #pragma unroll
    for (int r = 0; r < 4; ++r)
      qt[wv][(g * 4 + r) * 32 + f2 * 16 + li] = f2bf((aq[r] + biq) * ALPHA);
    // ---- K -> LDS tile, staged-group layout [gg 4][j 16][e'%8 8] ----
    f32x4 ak = wtile(xa, Wkb, fb, g, li);
    float bik = bk[fb * 16 + li];
    const int ggk = f2 * 2 + (li >> 3);
    #pragma unroll
    for (int r = 0; r < 4; ++r)
      kt[wv][ggk * 128 + (g * 4 + r) * 8 + (li & 7)] = f2bf(ak[r] + bik);
    // ---- V staged direct (already coalesced within the 1KB group) ----
    f32x4 av = wtile(xa, Wvb, fb, g, li);
    float biv = bv[fb * 16 + li];
    ushort4v pv;
    #pragma unroll
    for (int r = 0; r < 4; ++r) pv[r] = f2bf(av[r] + biv);
    *(ushort4v*)(VT + (tgbase + jtT * 4 + (fb >> 1)) * 512 +
                 ((g >> 1) * 32 + (fb & 1) * 16 + li) * 8 + (g & 1) * 4) = pv;
  }

  // ---- read back linear, store coalesced 16B ----
  short8 qv = *(const short8*)&qt[wv][lane * 8];
  *(short8*)(Qs + (size_t)(m0 + (lane >> 2)) * NE + fb0 * 16 + (lane & 3) * 8) = qv;
  short8 kv = *(const short8*)&kt[wv][lane * 8];
  *(short8*)(Kd + (tgbase + jtT * 4 + (fb0 >> 1)) * 512 + lane * 8) = kv;
}

// ---------------------------------------------------------------------------
// Kernel 2: flash attention — BYTE-IDENTICAL to the round-14/17 passing
// source. 256 blocks x 512 threads, 8 waves/CU. Block = 64 q-rows x 4
// key-splits. Reg-double-buffered asm global loads, counted vmcnt(8),
// defer-max.
// ---------------------------------------------------------------------------
__global__ __launch_bounds__(512, 2) void attn_k(
    const unsigned short* __restrict__ Qs, const unsigned short* __restrict__ Kd,
    const unsigned short* __restrict__ VT, float* __restrict__ Out) {
  __shared__ float smO[2 * SPLITS * 4 * 64 * 16];   // 128 KB
  __shared__ float smML[2 * SPLITS * 64];           // 2 KB

  const int lane = threadIdx.x & 63;
  const int wv   = threadIdx.x >> 6;             // 0..7
  const int qg   = wv >> 2;                      // q-group (0..1)
  const int sp   = wv & 3;                       // key split (0..3)
  const int bi   = blockIdx.x;                   // 0..255
  const int b    = (bi >> 1) & 3;                // batch tied to XCD pair
  const int within = ((bi >> 3) << 1) | (bi & 1);     // 0..63
  const int qb   = within * 64 + qg * 32;        // q-row base for this wave
  const int g    = lane >> 4, li = lane & 15;
  const int l31  = lane & 31, hi = lane >> 5;
  const bool qsel = (lane >> 4) & 1;

  // ---- Q B-frags via asm loads ----
  int4v q00, q01, q02, q03, q10, q11, q12, q13;
  {
    const unsigned short* q0 = Qs + (size_t)(b * NS + qb + li) * NE + g * 8;
    const unsigned short* q1 = Qs + (size_t)(b * NS + qb + 16 + li) * NE + g * 8;
    unsigned long long a0 = (unsigned long long)q0, a1 = (unsigned long long)q1;
    asm volatile("global_load_dwordx4 %0, %1, off"             : "=v"(q00) : "v"(a0));
    asm volatile("global_load_dwordx4 %0, %1, off offset:64"   : "=v"(q01) : "v"(a0));
    asm volatile("global_load_dwordx4 %0, %1, off offset:128"  : "=v"(q02) : "v"(a0));
    asm volatile("global_load_dwordx4 %0, %1, off offset:192"  : "=v"(q03) : "v"(a0));
    asm volatile("global_load_dwordx4 %0, %1, off"             : "=v"(q10) : "v"(a1));
    asm volatile("global_load_dwordx4 %0, %1, off offset:64"   : "=v"(q11) : "v"(a1));
    asm volatile("global_load_dwordx4 %0, %1, off offset:128"  : "=v"(q12) : "v"(a1));
    asm volatile("global_load_dwordx4 %0, %1, off offset:192"  : "=v"(q13) : "v"(a1));
  }

  const size_t stbase = (size_t)b * 64 * 16 * 512;       // shorts
  const int    kvoff  = sp * 2048 + lane * 8;            // shorts
  const unsigned long long kbase =
      (unsigned long long)(Kd + stbase + kvoff);
  const unsigned long long vbase =
      (unsigned long long)(VT + stbase + kvoff);

  int4v ka0, ka1, ka2, ka3, va0, va1, va2, va3;
  int4v kb0, kb1, kb2, kb3, vb0, vb1, vb2, vb3;

  #define LOAD_SET(K0,K1,K2,K3,V0,V1,V2,V3,T)                                   \
    {                                                                           \
      unsigned long long ka_ = kbase + (unsigned long long)(T) * 16384;         \
      unsigned long long va_ = vbase + (unsigned long long)(T) * 16384;         \
      asm volatile("global_load_dwordx4 %0, %1, off"             : "=v"(K0) : "v"(ka_)); \
      asm volatile("global_load_dwordx4 %0, %1, off offset:1024" : "=v"(K1) : "v"(ka_)); \
      asm volatile("global_load_dwordx4 %0, %1, off offset:2048" : "=v"(K2) : "v"(ka_)); \
      asm volatile("global_load_dwordx4 %0, %1, off offset:3072" : "=v"(K3) : "v"(ka_)); \
      asm volatile("global_load_dwordx4 %0, %1, off"             : "=v"(V0) : "v"(va_)); \
      asm volatile("global_load_dwordx4 %0, %1, off offset:1024" : "=v"(V1) : "v"(va_)); \
      asm volatile("global_load_dwordx4 %0, %1, off offset:2048" : "=v"(V2) : "v"(va_)); \
      asm volatile("global_load_dwordx4 %0, %1, off offset:3072" : "=v"(V3) : "v"(va_)); \
    }
  #define LOAD_A(T) LOAD_SET(ka0,ka1,ka2,ka3,va0,va1,va2,va3,T)
  #define LOAD_B(T) LOAD_SET(kb0,kb1,kb2,kb3,vb0,vb1,vb2,vb3,T)
  #define WAIT8 asm volatile("s_waitcnt vmcnt(8)" ::: "memory"); \
                __builtin_amdgcn_sched_barrier(0);

  f32x16 o[4];
  #pragma unroll
  for (int et = 0; et < 4; ++et)
    #pragma unroll
    for (int r = 0; r < 16; ++r) o[et][r] = 0.f;
  float m0 = -1e30f, m1 = -1e30f, L0 = 0.f, L1 = 0.f;

  const int src01 = (lane & 15) | (lane & 32);
  const int src23 = src01 + 16;

  #define BODY(K0,K1,K2,K3,V0,V1,V2,V3)                                        \
  {                                                                            \
    f32x4 s0 = {0.f, 0.f, 0.f, 0.f}, s1 = {0.f, 0.f, 0.f, 0.f};                \
    __builtin_amdgcn_s_setprio(1);                                             \
    s0 = __builtin_amdgcn_mfma_f32_16x16x32_bf16(as_s8(K0), as_s8(q00), s0, 0,0,0); \
    s1 = __builtin_amdgcn_mfma_f32_16x16x32_bf16(as_s8(K0), as_s8(q10), s1, 0,0,0); \
    s0 = __builtin_amdgcn_mfma_f32_16x16x32_bf16(as_s8(K1), as_s8(q01), s0, 0,0,0); \
    s1 = __builtin_amdgcn_mfma_f32_16x16x32_bf16(as_s8(K1), as_s8(q11), s1, 0,0,0); \
    s0 = __builtin_amdgcn_mfma_f32_16x16x32_bf16(as_s8(K2), as_s8(q02), s0, 0,0,0); \
    s1 = __builtin_amdgcn_mfma_f32_16x16x32_bf16(as_s8(K2), as_s8(q12), s1, 0,0,0); \
    s0 = __builtin_amdgcn_mfma_f32_16x16x32_bf16(as_s8(K3), as_s8(q03), s0, 0,0,0); \
    s1 = __builtin_amdgcn_mfma_f32_16x16x32_bf16(as_s8(K3), as_s8(q13), s1, 0,0,0); \
    __builtin_amdgcn_s_setprio(0);                                             \
    float tm0 = fmaxf(fmaxf(s0[0], s0[1]), fmaxf(s0[2], s0[3]));               \
    float tm1 = fmaxf(fmaxf(s1[0], s1[1]), fmaxf(s1[2], s1[3]));               \
    if (__any(fmaxf(tm0 - m0, tm1 - m1) > DEFER_THR)) {                        \
      tm0 = fmaxf(tm0, __shfl_xor(tm0, 16));                                   \
      tm1 = fmaxf(tm1, __shfl_xor(tm1, 16));                                   \
      tm0 = fmaxf(tm0, __shfl_xor(tm0, 32));                                   \
      tm1 = fmaxf(tm1, __shfl_xor(tm1, 32));                                   \
      float mn0 = fmaxf(m0, tm0), c0 = __builtin_amdgcn_exp2f(m0 - mn0);       \
      float mn1 = fmaxf(m1, tm1), c1 = __builtin_amdgcn_exp2f(m1 - mn1);       \
      const float cmy = qsel ? c1 : c0;                                        \
      o[0] = o[0] * cmy; o[1] = o[1] * cmy;                                    \
      o[2] = o[2] * cmy; o[3] = o[3] * cmy;                                    \
      L0 *= c0; L1 *= c1; m0 = mn0; m1 = mn1;                                  \
    }                                                                          \
    float p00 = __builtin_amdgcn_exp2f(s0[0] - m0);                            \
    float p01 = __builtin_amdgcn_exp2f(s0[1] - m0);                            \
    float p02 = __builtin_amdgcn_exp2f(s0[2] - m0);                            \
    float p03 = __builtin_amdgcn_exp2f(s0[3] - m0);                            \
    float p10 = __builtin_amdgcn_exp2f(s1[0] - m1);                            \
    float p11 = __builtin_amdgcn_exp2f(s1[1] - m1);                            \
    float p12 = __builtin_amdgcn_exp2f(s1[2] - m1);                            \
    float p13 = __builtin_amdgcn_exp2f(s1[3] - m1);                            \
    L0 += (p00 + p01) + (p02 + p03);                                           \
    L1 += (p10 + p11) + (p12 + p13);                                           \
    unsigned int pk00 = pack2bf(p00, p01);                                     \
    unsigned int pk01 = pack2bf(p02, p03);                                     \
    unsigned int pk10 = pack2bf(p10, p11);                                     \
    unsigned int pk11 = pack2bf(p12, p13);                                     \
    int ta, tb, w0, w1, w2, w3;                                                \
    ta = __shfl((int)pk00, src01); tb = __shfl((int)pk10, src01);              \
    w0 = qsel ? tb : ta;                                                       \
    ta = __shfl((int)pk01, src01); tb = __shfl((int)pk11, src01);              \
    w1 = qsel ? tb : ta;                                                       \
    ta = __shfl((int)pk00, src23); tb = __shfl((int)pk10, src23);              \
    w2 = qsel ? tb : ta;                                                       \
    ta = __shfl((int)pk01, src23); tb = __shfl((int)pk11, src23);              \
    w3 = qsel ? tb : ta;                                                       \
    union { int4v i4; short8 s8; } pb;                                         \
    pb.i4 = (int4v){w0, w1, w2, w3};                                           \
    __builtin_amdgcn_s_setprio(1);                                             \
    o[0] = __builtin_amdgcn_mfma_f32_32x32x16_bf16(as_s8(V0), pb.s8, o[0], 0,0,0); \
    o[1] = __builtin_amdgcn_mfma_f32_32x32x16_bf16(as_s8(V1), pb.s8, o[1], 0,0,0); \
    o[2] = __builtin_amdgcn_mfma_f32_32x32x16_bf16(as_s8(V2), pb.s8, o[2], 0,0,0); \
    o[3] = __builtin_amdgcn_mfma_f32_32x32x16_bf16(as_s8(V3), pb.s8, o[3], 0,0,0); \
    __builtin_amdgcn_s_setprio(0);                                             \
  }

  LOAD_A(0);
  WAIT8;   // Q frags ready; tile 0 in flight

  #pragma unroll 1
  for (int t2 = 0; t2 < NIT; t2 += 2) {
    LOAD_B(t2 + 1);
    WAIT8;
    BODY(ka0, ka1, ka2, ka3, va0, va1, va2, va3)
    LOAD_A((t2 + 2) & (NIT - 1));
    WAIT8;
    BODY(kb0, kb1, kb2, kb3, vb0, vb1, vb2, vb3)
  }

  __syncthreads();

  // ---- epilogue: publish split partials ([qg][sp][et][lane][16]) ----
  L0 += __shfl_xor(L0, 16); L0 += __shfl_xor(L0, 32);
  L1 += __shfl_xor(L1, 16); L1 += __shfl_xor(L1, 32);
  #pragma unroll
  for (int et = 0; et < 4; ++et)
    #pragma unroll
    for (int rq = 0; rq < 4; ++rq) {
      float4 v;
      v.x = o[et][rq * 4 + 0]; v.y = o[et][rq * 4 + 1];
      v.z = o[et][rq * 4 + 2]; v.w = o[et][rq * 4 + 3];
      *(float4*)(smO + (size_t)(((qg * SPLITS + sp) * 4 + et) * 64 + lane) * 16 + rq * 4) = v;
    }
  if (lane < 16) {
    smML[(qg * SPLITS + sp) * 64 + lane]      = m0;
    smML[(qg * SPLITS + sp) * 64 + 16 + lane] = m1;
    smML[(qg * SPLITS + sp) * 64 + 32 + lane] = L0;
    smML[(qg * SPLITS + sp) * 64 + 48 + lane] = L1;
  }
  __syncthreads();

  // ---- combine: wave wv handles (q-group wv>>2, e-block wv&3) ----
  const int cqg = wv >> 2, cet = wv & 3;
  float ms[SPLITS], Ls[SPLITS];
  #pragma unroll
  for (int sp2 = 0; sp2 < SPLITS; ++sp2) {
    ms[sp2] = smML[(cqg * SPLITS + sp2) * 64 + l31];
    Ls[sp2] = smML[(cqg * SPLITS + sp2) * 64 + 32 + l31];
  }
  float M = fmaxf(fmaxf(ms[0], ms[1]), fmaxf(ms[2], ms[3]));
  float W[SPLITS], Ltot = 0.f;
  #pragma unroll
  for (int sp2 = 0; sp2 < SPLITS; ++sp2) {
    W[sp2] = __builtin_amdgcn_exp2f(ms[sp2] - M);
    Ltot += W[sp2] * Ls[sp2];
  }
  const float rL = 1.f / Ltot;
  float* Orow = Out + (size_t)(b * NS + within * 64 + cqg * 32 + l31) * NE + cet * 32;
  #pragma unroll
  for (int rq = 0; rq < 4; ++rq) {
    float4 acc = make_float4(0.f, 0.f, 0.f, 0.f);
    #pragma unroll
    for (int sp2 = 0; sp2 < SPLITS; ++sp2) {
      float4 v = *(const float4*)(smO +
          (size_t)(((cqg * SPLITS + sp2) * 4 + cet) * 64 + lane) * 16 + rq * 4);
      acc.x += W[sp2] * v.x; acc.y += W[sp2] * v.y;
      acc.z += W[sp2] * v.z; acc.w += W[sp2] * v.w;
    }
    acc.x *= rL; acc.y *= rL; acc.z *= rL; acc.w *= rL;
    *(float4*)(Orow + 8 * rq + 4 * hi) = acc;
  }
}

extern "C" void kernel_launch(void* const* d_in, const int* in_sizes, int n_in,
                              void* d_out, int out_size, void* d_ws, size_t ws_size,
                              hipStream_t stream) {
  const float* X  = (const float*)d_in[0];
  // d_in[1] = context : unused (per-row bias is softmax-invariant)
  const float* Wq = (const float*)d_in[2];
  const float* bq = (const float*)d_in[3];
  const float* Wk = (const float*)d_in[4];
  const float* bk = (const float*)d_in[5];
  const float* Wv = (const float*)d_in[6];
  const float* bv = (const float*)d_in[7];
  // d_in[8] = Wc, d_in[9] = bc : unused

  unsigned short* Qs  = (unsigned short*)d_ws;                // 4 MB
  unsigned short* Kd  = Qs + (size_t)NB * NS * NE;            // 4 MB (staged)
  unsigned short* VT  = Kd + (size_t)NB * NS * NE;            // 4 MB (staged)
  unsigned short* Wqb = VT + (size_t)NB * NS * NE;            // 32 KB x3
  unsigned short* Wkb = Wqb + NE * NE;
  unsigned short* Wvb = Wkb + NE * NE;

  prep_k<<<48, 256, 0, stream>>>(Wq, Wk, Wv, Wqb, Wkb, Wvb);
  qkv_proj_k<<<1024, 256, 0, stream>>>(X, Wqb, bq, Wkb, bk, Wvb, bv, Qs, Kd, VT);
  attn_k<<<256, 512, 0, stream>>>(Qs, Kd, VT, (float*)d_out);
}

// Round 19
// 76.461 us; speedup vs baseline: 1.1026x; 1.0603x over previous
//
#include <hip/hip_runtime.h>
#include <hip/hip_bf16.h>

typedef short short8 __attribute__((ext_vector_type(8)));
typedef float f32x4 __attribute__((ext_vector_type(4)));
typedef float f32x16 __attribute__((ext_vector_type(16)));
typedef int int4v __attribute__((ext_vector_type(4)));
typedef unsigned short ushort4v __attribute__((ext_vector_type(4)));

#define NB 4
#define NS 4096
#define NE 128
#define ALPHA 0.1275174468f  /* log2(e)/sqrt(128) */
#define KVB 64                 /* keys per tile */
#define NIT (NS / KVB)         /* 64 */
#define SPLITS 4               /* 16-key splits */
#define DEFER_THR 8.0f         /* log2 units: P bounded by 2^8 */

static __device__ __forceinline__ unsigned short f2bf(float f) {
  union { float f; unsigned int u; } v; v.f = f;
  unsigned int u = v.u;
  return (unsigned short)((u + 0x7FFFu + ((u >> 16) & 1u)) >> 16);
}
static __device__ __forceinline__ unsigned int pack2bf(float a, float b) {
  union { __hip_bfloat162 h; unsigned int u; } v;
  v.h = __float22bfloat162_rn(float2{a, b});
  return v.u;
}
static __device__ __forceinline__ short8 as_s8(int4v x) {
  union { int4v i; short8 s; } u; u.i = x; return u.s;
}

// ---------------------------------------------------------------------------
// Staged ws layouts (per batch, per 64-key tile, 16 groups x 1KB, contiguous):
//  K group jt*4+ks, lane=gg*16+li: K[j=jt*16+li][e=ks*32+gg*8+..7]
//  V group sp*4+et, lane=hi*32+l31: V[j=sp*16+hi*8+..7][e=et*32+l31]
// Weights: FRAGMENT-MAJOR: Wf[(fb*4+ks)*512 + lane*8 + e'] =
//          W[fb*16+(lane&15)][ks*32+(lane>>4)*8+e']  (1KB linear per frag)
// ---------------------------------------------------------------------------

// Kernel 0: f32 weights -> bf16 fragment-major (3 x 32KB).
__global__ __launch_bounds__(256) void prep_k(
    const float* __restrict__ Wq, const float* __restrict__ Wk,
    const float* __restrict__ Wv,
    unsigned short* __restrict__ Wqf, unsigned short* __restrict__ Wkf,
    unsigned short* __restrict__ Wvf) {
  int i = blockIdx.x * 256 + threadIdx.x;          // 0..12287
  const float* srcs[3] = {Wq, Wk, Wv};
  unsigned short* dsts[3] = {Wqf, Wkf, Wvf};
  int m = i >> 12, j = i & 4095;                   // j indexes 4-short chunks
  int group = j >> 7;                              // fb*4+ks
  int l     = (j >> 1) & 63;                       // lane
  int e0    = (j & 1) * 4;
  int fb = group >> 2, ks = group & 3;
  int r  = fb * 16 + (l & 15);
  int c  = ks * 32 + (l >> 4) * 8 + e0;
  float4 v = *(const float4*)(srcs[m] + r * NE + c);
  ushort4v o;
  o[0] = f2bf(v.x); o[1] = f2bf(v.y); o[2] = f2bf(v.z); o[3] = f2bf(v.w);
  *(ushort4v*)(dsts[m] + (size_t)j * 4) = o;
}

// wtile with fragment-major weights: one linear 1KB burst per (fb,ks).
static __device__ __forceinline__ f32x4 wtile(const short8 xa[4],
                                              const unsigned short* __restrict__ Wf,
                                              int fb, int lane) {
  f32x4 acc = {0.f, 0.f, 0.f, 0.f};
  #pragma unroll
  for (int ks = 0; ks < 4; ++ks) {
    short8 wf = *(const short8*)(Wf + ((fb * 4 + ks) << 9) + lane * 8);
    acc = __builtin_amdgcn_mfma_f32_16x16x32_bf16(xa[ks], wf, acc, 0, 0, 0);
  }
  return acc;
}

// ---------------------------------------------------------------------------
// Kernel 1: fused QKV projection. 512 blocks, 4 fb per block (X loaded once
// per tile). Fragment-major weight loads (linear 1KB). Q/K routed through
// per-wave 2KB LDS tiles -> all global stores are coalesced 16B bursts.
// ---------------------------------------------------------------------------
__global__ __launch_bounds__(256, 4) void qkv_proj_k(
    const float* __restrict__ X,
    const unsigned short* __restrict__ Wqf, const float* __restrict__ bq,
    const unsigned short* __restrict__ Wkf, const float* __restrict__ bk,
    const unsigned short* __restrict__ Wvf, const float* __restrict__ bv,
    unsigned short* __restrict__ Qs, unsigned short* __restrict__ Kd,
    unsigned short* __restrict__ VT) {
  __shared__ __align__(16) unsigned short qt[4][1024];   // per-wave 2KB tiles
  __shared__ __align__(16) unsigned short kt[4][1024];

  const int lane = threadIdx.x & 63;
  const int wv   = threadIdx.x >> 6;
  const int tile = (blockIdx.x >> 1) * 4 + wv;   // 0..1023
  const int fb0  = (blockIdx.x & 1) * 4;         // output half (4 fb)
  const int m0   = tile * 16;
  const int g    = lane >> 4, li = lane & 15;

  short8 xa[4];
  #pragma unroll
  for (int ks = 0; ks < 4; ++ks) {
    const float* xp = X + (size_t)(m0 + li) * NE + ks * 32 + g * 8;
    float4 x0 = *(const float4*)xp;
    float4 x1 = *(const float4*)(xp + 4);
    short8 t;
    t[0] = (short)f2bf(x0.x); t[1] = (short)f2bf(x0.y);
    t[2] = (short)f2bf(x0.z); t[3] = (short)f2bf(x0.w);
    t[4] = (short)f2bf(x1.x); t[5] = (short)f2bf(x1.y);
    t[6] = (short)f2bf(x1.z); t[7] = (short)f2bf(x1.w);
    xa[ks] = t;
  }

  const int bb  = m0 >> 12;              // batch
  const int tT  = (m0 & 4095) >> 6;      // 64-key tile within batch
  const int jtT = (m0 >> 4) & 3;         // 16-key subtile (= sp)
  const size_t tgbase = ((size_t)(bb * 64 + tT)) * 16;   // group base (x512)

  #pragma unroll
  for (int f2 = 0; f2 < 4; ++f2) {
    const int fb = fb0 + f2;
    // ---- Q -> LDS tile, row-major [j 16][e' 64] ----
    f32x4 aq = wtile(xa, Wqf, fb, lane);
    float biq = bq[fb * 16 + li];
    #pragma unroll
    for (int r = 0; r < 4; ++r)
      qt[wv][(g * 4 + r) * 64 + f2 * 16 + li] = f2bf((aq[r] + biq) * ALPHA);
    // ---- K -> LDS tile, staged-group layout [h 2][gg 4][j 16][e'%8 8] ----
    f32x4 ak = wtile(xa, Wkf, fb, lane);
    float bik = bk[fb * 16 + li];
    const int hk  = f2 >> 1;                 // group-pair index
    const int ggk = (fb & 1) * 2 + (li >> 3);
    #pragma unroll
    for (int r = 0; r < 4; ++r)
      kt[wv][hk * 512 + ggk * 128 + (g * 4 + r) * 8 + (li & 7)] = f2bf(ak[r] + bik);
    // ---- V staged direct (coalesced within the 1KB group) ----
    f32x4 av = wtile(xa, Wvf, fb, lane);
    float biv = bv[fb * 16 + li];
    ushort4v pv;
    #pragma unroll
    for (int r = 0; r < 4; ++r) pv[r] = f2bf(av[r] + biv);
    *(ushort4v*)(VT + (tgbase + jtT * 4 + (fb >> 1)) * 512 +
                 ((g >> 1) * 32 + (fb & 1) * 16 + li) * 8 + (g & 1) * 4) = pv;
  }

  // ---- read back linear, store coalesced 16B (2 per lane each) ----
  #pragma unroll
  for (int r2 = 0; r2 < 2; ++r2) {
    short8 qv = *(const short8*)&qt[wv][lane * 16 + r2 * 8];
    // flat = lane*16 + r2*8 ; j = flat>>6 ; col = flat&63
    *(short8*)(Qs + (size_t)(m0 + (lane >> 2)) * NE + fb0 * 16 +
               (lane & 3) * 16 + r2 * 8) = qv;
    short8 kv = *(const short8*)&kt[wv][r2 * 512 + lane * 8];
    *(short8*)(Kd + (tgbase + jtT * 4 + (fb0 >> 1) + r2) * 512 + lane * 8) = kv;
  }
}

// ---------------------------------------------------------------------------
// Kernel 2: flash attention — BYTE-IDENTICAL to the round-14/17/18 passing
// source. 256 blocks x 512 threads, 8 waves/CU. Block = 64 q-rows x 4
// key-splits. Reg-double-buffered asm global loads, counted vmcnt(8),
// defer-max.
// ---------------------------------------------------------------------------
__global__ __launch_bounds__(512, 2) void attn_k(
    const unsigned short* __restrict__ Qs, const unsigned short* __restrict__ Kd,
    const unsigned short* __restrict__ VT, float* __restrict__ Out) {
  __shared__ float smO[2 * SPLITS * 4 * 64 * 16];   // 128 KB
  __shared__ float smML[2 * SPLITS * 64];           // 2 KB

  const int lane = threadIdx.x & 63;
  const int wv   = threadIdx.x >> 6;             // 0..7
  const int qg   = wv >> 2;                      // q-group (0..1)
  const int sp   = wv & 3;                       // key split (0..3)
  const int bi   = blockIdx.x;                   // 0..255
  const int b    = (bi >> 1) & 3;                // batch tied to XCD pair
  const int within = ((bi >> 3) << 1) | (bi & 1);     // 0..63
  const int qb   = within * 64 + qg * 32;        // q-row base for this wave
  const int g    = lane >> 4, li = lane & 15;
  const int l31  = lane & 31, hi = lane >> 5;
  const bool qsel = (lane >> 4) & 1;

  // ---- Q B-frags via asm loads ----
  int4v q00, q01, q02, q03, q10, q11, q12, q13;
  {
    const unsigned short* q0 = Qs + (size_t)(b * NS + qb + li) * NE + g * 8;
    const unsigned short* q1 = Qs + (size_t)(b * NS + qb + 16 + li) * NE + g * 8;
    unsigned long long a0 = (unsigned long long)q0, a1 = (unsigned long long)q1;
    asm volatile("global_load_dwordx4 %0, %1, off"             : "=v"(q00) : "v"(a0));
    asm volatile("global_load_dwordx4 %0, %1, off offset:64"   : "=v"(q01) : "v"(a0));
    asm volatile("global_load_dwordx4 %0, %1, off offset:128"  : "=v"(q02) : "v"(a0));
    asm volatile("global_load_dwordx4 %0, %1, off offset:192"  : "=v"(q03) : "v"(a0));
    asm volatile("global_load_dwordx4 %0, %1, off"             : "=v"(q10) : "v"(a1));
    asm volatile("global_load_dwordx4 %0, %1, off offset:64"   : "=v"(q11) : "v"(a1));
    asm volatile("global_load_dwordx4 %0, %1, off offset:128"  : "=v"(q12) : "v"(a1));
    asm volatile("global_load_dwordx4 %0, %1, off offset:192"  : "=v"(q13) : "v"(a1));
  }

  const size_t stbase = (size_t)b * 64 * 16 * 512;       // shorts
  const int    kvoff  = sp * 2048 + lane * 8;            // shorts
  const unsigned long long kbase =
      (unsigned long long)(Kd + stbase + kvoff);
  const unsigned long long vbase =
      (unsigned long long)(VT + stbase + kvoff);

  int4v ka0, ka1, ka2, ka3, va0, va1, va2, va3;
  int4v kb0, kb1, kb2, kb3, vb0, vb1, vb2, vb3;

  #define LOAD_SET(K0,K1,K2,K3,V0,V1,V2,V3,T)                                   \
    {                                                                           \
      unsigned long long ka_ = kbase + (unsigned long long)(T) * 16384;         \
      unsigned long long va_ = vbase + (unsigned long long)(T) * 16384;         \
      asm volatile("global_load_dwordx4 %0, %1, off"             : "=v"(K0) : "v"(ka_)); \
      asm volatile("global_load_dwordx4 %0, %1, off offset:1024" : "=v"(K1) : "v"(ka_)); \
      asm volatile("global_load_dwordx4 %0, %1, off offset:2048" : "=v"(K2) : "v"(ka_)); \
      asm volatile("global_load_dwordx4 %0, %1, off offset:3072" : "=v"(K3) : "v"(ka_)); \
      asm volatile("global_load_dwordx4 %0, %1, off"             : "=v"(V0) : "v"(va_)); \
      asm volatile("global_load_dwordx4 %0, %1, off offset:1024" : "=v"(V1) : "v"(va_)); \
      asm volatile("global_load_dwordx4 %0, %1, off offset:2048" : "=v"(V2) : "v"(va_)); \
      asm volatile("global_load_dwordx4 %0, %1, off offset:3072" : "=v"(V3) : "v"(va_)); \
    }
  #define LOAD_A(T) LOAD_SET(ka0,ka1,ka2,ka3,va0,va1,va2,va3,T)
  #define LOAD_B(T) LOAD_SET(kb0,kb1,kb2,kb3,vb0,vb1,vb2,vb3,T)
  #define WAIT8 asm volatile("s_waitcnt vmcnt(8)" ::: "memory"); \
                __builtin_amdgcn_sched_barrier(0);

  f32x16 o[4];
  #pragma unroll
  for (int et = 0; et < 4; ++et)
    #pragma unroll
    for (int r = 0; r < 16; ++r) o[et][r] = 0.f;
  float m0 = -1e30f, m1 = -1e30f, L0 = 0.f, L1 = 0.f;

  const int src01 = (lane & 15) | (lane & 32);
  const int src23 = src01 + 16;

  #define BODY(K0,K1,K2,K3,V0,V1,V2,V3)                                        \
  {                                                                            \
    f32x4 s0 = {0.f, 0.f, 0.f, 0.f}, s1 = {0.f, 0.f, 0.f, 0.f};                \
    __builtin_amdgcn_s_setprio(1);                                             \
    s0 = __builtin_amdgcn_mfma_f32_16x16x32_bf16(as_s8(K0), as_s8(q00), s0, 0,0,0); \
    s1 = __builtin_amdgcn_mfma_f32_16x16x32_bf16(as_s8(K0), as_s8(q10), s1, 0,0,0); \
    s0 = __builtin_amdgcn_mfma_f32_16x16x32_bf16(as_s8(K1), as_s8(q01), s0, 0,0,0); \
    s1 = __builtin_amdgcn_mfma_f32_16x16x32_bf16(as_s8(K1), as_s8(q11), s1, 0,0,0); \
    s0 = __builtin_amdgcn_mfma_f32_16x16x32_bf16(as_s8(K2), as_s8(q02), s0, 0,0,0); \
    s1 = __builtin_amdgcn_mfma_f32_16x16x32_bf16(as_s8(K2), as_s8(q12), s1, 0,0,0); \
    s0 = __builtin_amdgcn_mfma_f32_16x16x32_bf16(as_s8(K3), as_s8(q03), s0, 0,0,0); \
    s1 = __builtin_amdgcn_mfma_f32_16x16x32_bf16(as_s8(K3), as_s8(q13), s1, 0,0,0); \
    __builtin_amdgcn_s_setprio(0);                                             \
    float tm0 = fmaxf(fmaxf(s0[0], s0[1]), fmaxf(s0[2], s0[3]));               \
    float tm1 = fmaxf(fmaxf(s1[0], s1[1]), fmaxf(s1[2], s1[3]));               \
    if (__any(fmaxf(tm0 - m0, tm1 - m1) > DEFER_THR)) {                        \
      tm0 = fmaxf(tm0, __shfl_xor(tm0, 16));                                   \
      tm1 = fmaxf(tm1, __shfl_xor(tm1, 16));                                   \
      tm0 = fmaxf(tm0, __shfl_xor(tm0, 32));                                   \
      tm1 = fmaxf(tm1, __shfl_xor(tm1, 32));                                   \
      float mn0 = fmaxf(m0, tm0), c0 = __builtin_amdgcn_exp2f(m0 - mn0);       \
      float mn1 = fmaxf(m1, tm1), c1 = __builtin_amdgcn_exp2f(m1 - mn1);       \
      const float cmy = qsel ? c1 : c0;                                        \
      o[0] = o[0] * cmy; o[1] = o[1] * cmy;                                    \
      o[2] = o[2] * cmy; o[3] = o[3] * cmy;                                    \
      L0 *= c0; L1 *= c1; m0 = mn0; m1 = mn1;                                  \
    }                                                                          \
    float p00 = __builtin_amdgcn_exp2f(s0[0] - m0);                            \
    float p01 = __builtin_amdgcn_exp2f(s0[1] - m0);                            \
    float p02 = __builtin_amdgcn_exp2f(s0[2] - m0);                            \
    float p03 = __builtin_amdgcn_exp2f(s0[3] - m0);                            \
    float p10 = __builtin_amdgcn_exp2f(s1[0] - m1);                            \
    float p11 = __builtin_amdgcn_exp2f(s1[1] - m1);                            \
    float p12 = __builtin_amdgcn_exp2f(s1[2] - m1);                            \
    float p13 = __builtin_amdgcn_exp2f(s1[3] - m1);                            \
    L0 += (p00 + p01) + (p02 + p03);                                           \
    L1 += (p10 + p11) + (p12 + p13);                                           \
    unsigned int pk00 = pack2bf(p00, p01);                                     \
    unsigned int pk01 = pack2bf(p02, p03);                                     \
    unsigned int pk10 = pack2bf(p10, p11);                                     \
    unsigned int pk11 = pack2bf(p12, p13);                                     \
    int ta, tb, w0, w1, w2, w3;                                                \
    ta = __shfl((int)pk00, src01); tb = __shfl((int)pk10, src01);              \
    w0 = qsel ? tb : ta;                                                       \
    ta = __shfl((int)pk01, src01); tb = __shfl((int)pk11, src01);              \
    w1 = qsel ? tb : ta;                                                       \
    ta = __shfl((int)pk00, src23); tb = __shfl((int)pk10, src23);              \
    w2 = qsel ? tb : ta;                                                       \
    ta = __shfl((int)pk01, src23); tb = __shfl((int)pk11, src23);              \
    w3 = qsel ? tb : ta;                                                       \
    union { int4v i4; short8 s8; } pb;                                         \
    pb.i4 = (int4v){w0, w1, w2, w3};                                           \
    __builtin_amdgcn_s_setprio(1);                                             \
    o[0] = __builtin_amdgcn_mfma_f32_32x32x16_bf16(as_s8(V0), pb.s8, o[0], 0,0,0); \
    o[1] = __builtin_amdgcn_mfma_f32_32x32x16_bf16(as_s8(V1), pb.s8, o[1], 0,0,0); \
    o[2] = __builtin_amdgcn_mfma_f32_32x32x16_bf16(as_s8(V2), pb.s8, o[2], 0,0,0); \
    o[3] = __builtin_amdgcn_mfma_f32_32x32x16_bf16(as_s8(V3), pb.s8, o[3], 0,0,0); \
    __builtin_amdgcn_s_setprio(0);                                             \
  }

  LOAD_A(0);
  WAIT8;   // Q frags ready; tile 0 in flight

  #pragma unroll 1
  for (int t2 = 0; t2 < NIT; t2 += 2) {
    LOAD_B(t2 + 1);
    WAIT8;
    BODY(ka0, ka1, ka2, ka3, va0, va1, va2, va3)
    LOAD_A((t2 + 2) & (NIT - 1));
    WAIT8;
    BODY(kb0, kb1, kb2, kb3, vb0, vb1, vb2, vb3)
  }

  __syncthreads();

  // ---- epilogue: publish split partials ([qg][sp][et][lane][16]) ----
  L0 += __shfl_xor(L0, 16); L0 += __shfl_xor(L0, 32);
  L1 += __shfl_xor(L1, 16); L1 += __shfl_xor(L1, 32);
  #pragma unroll
  for (int et = 0; et < 4; ++et)
    #pragma unroll
    for (int rq = 0; rq < 4; ++rq) {
      float4 v;
      v.x = o[et][rq * 4 + 0]; v.y = o[et][rq * 4 + 1];
      v.z = o[et][rq * 4 + 2]; v.w = o[et][rq * 4 + 3];
      *(float4*)(smO + (size_t)(((qg * SPLITS + sp) * 4 + et) * 64 + lane) * 16 + rq * 4) = v;
    }
  if (lane < 16) {
    smML[(qg * SPLITS + sp) * 64 + lane]      = m0;
    smML[(qg * SPLITS + sp) * 64 + 16 + lane] = m1;
    smML[(qg * SPLITS + sp) * 64 + 32 + lane] = L0;
    smML[(qg * SPLITS + sp) * 64 + 48 + lane] = L1;
  }
  __syncthreads();

  // ---- combine: wave wv handles (q-group wv>>2, e-block wv&3) ----
  const int cqg = wv >> 2, cet = wv & 3;
  float ms[SPLITS], Ls[SPLITS];
  #pragma unroll
  for (int sp2 = 0; sp2 < SPLITS; ++sp2) {
    ms[sp2] = smML[(cqg * SPLITS + sp2) * 64 + l31];
    Ls[sp2] = smML[(cqg * SPLITS + sp2) * 64 + 32 + l31];
  }
  float M = fmaxf(fmaxf(ms[0], ms[1]), fmaxf(ms[2], ms[3]));
  float W[SPLITS], Ltot = 0.f;
  #pragma unroll
  for (int sp2 = 0; sp2 < SPLITS; ++sp2) {
    W[sp2] = __builtin_amdgcn_exp2f(ms[sp2] - M);
    Ltot += W[sp2] * Ls[sp2];
  }
  const float rL = 1.f / Ltot;
  float* Orow = Out + (size_t)(b * NS + within * 64 + cqg * 32 + l31) * NE + cet * 32;
  #pragma unroll
  for (int rq = 0; rq < 4; ++rq) {
    float4 acc = make_float4(0.f, 0.f, 0.f, 0.f);
    #pragma unroll
    for (int sp2 = 0; sp2 < SPLITS; ++sp2) {
      float4 v = *(const float4*)(smO +
          (size_t)(((cqg * SPLITS + sp2) * 4 + cet) * 64 + lane) * 16 + rq * 4);
      acc.x += W[sp2] * v.x; acc.y += W[sp2] * v.y;
      acc.z += W[sp2] * v.z; acc.w += W[sp2] * v.w;
    }
    acc.x *= rL; acc.y *= rL; acc.z *= rL; acc.w *= rL;
    *(float4*)(Orow + 8 * rq + 4 * hi) = acc;
  }
}

extern "C" void kernel_launch(void* const* d_in, const int* in_sizes, int n_in,
                              void* d_out, int out_size, void* d_ws, size_t ws_size,
                              hipStream_t stream) {
  const float* X  = (const float*)d_in[0];
  // d_in[1] = context : unused (per-row bias is softmax-invariant)
  const float* Wq = (const float*)d_in[2];
  const float* bq = (const float*)d_in[3];
  const float* Wk = (const float*)d_in[4];
  const float* bk = (const float*)d_in[5];
  const float* Wv = (const float*)d_in[6];
  const float* bv = (const float*)d_in[7];
  // d_in[8] = Wc, d_in[9] = bc : unused

  unsigned short* Qs  = (unsigned short*)d_ws;                // 4 MB
  unsigned short* Kd  = Qs + (size_t)NB * NS * NE;            // 4 MB (staged)
  unsigned short* VT  = Kd + (size_t)NB * NS * NE;            // 4 MB (staged)
  unsigned short* Wqf = VT + (size_t)NB * NS * NE;            // 32 KB x3 (frag-major)
  unsigned short* Wkf = Wqf + NE * NE;
  unsigned short* Wvf = Wkf + NE * NE;

  prep_k<<<48, 256, 0, stream>>>(Wq, Wk, Wv, Wqf, Wkf, Wvf);
  qkv_proj_k<<<512, 256, 0, stream>>>(X, Wqf, bq, Wkf, bk, Wvf, bv, Qs, Kd, VT);
  attn_k<<<256, 512, 0, stream>>>(Qs, Kd, VT, (float*)d_out);
}

// Round 22
// 76.198 us; speedup vs baseline: 1.1064x; 1.0035x over previous
//
#include <hip/hip_runtime.h>
#include <hip/hip_bf16.h>

typedef short short8 __attribute__((ext_vector_type(8)));
typedef float f32x4 __attribute__((ext_vector_type(4)));
typedef float f32x16 __attribute__((ext_vector_type(16)));
typedef int int4v __attribute__((ext_vector_type(4)));
typedef unsigned short ushort4v __attribute__((ext_vector_type(4)));

#define NB 4
#define NS 4096
#define NE 128
#define ALPHA 0.1275174468f  /* log2(e)/sqrt(128) */
#define KVB 64                 /* keys per tile */
#define NIT (NS / KVB)         /* 64 */
#define SPLITS 4               /* 16-key splits */
#define DEFER_THR 8.0f         /* log2 units: P bounded by 2^8 */

static __device__ __forceinline__ unsigned short f2bf(float f) {
  union { float f; unsigned int u; } v; v.f = f;
  unsigned int u = v.u;
  return (unsigned short)((u + 0x7FFFu + ((u >> 16) & 1u)) >> 16);
}
static __device__ __forceinline__ unsigned int pack2bf(float a, float b) {
  union { __hip_bfloat162 h; unsigned int u; } v;
  v.h = __float22bfloat162_rn(float2{a, b});
  return v.u;
}
static __device__ __forceinline__ short8 as_s8(int4v x) {
  union { int4v i; short8 s; } u; u.i = x; return u.s;
}

// ---------------------------------------------------------------------------
// Staged ws layouts (per batch, per 64-key tile, 16 groups x 1KB, contiguous):
//  K group jt*4+ks, lane=gg*16+li: K[j=jt*16+li][e=ks*32+gg*8+..7]
//  V group sp*4+et, lane=hi*32+l31: V[j=sp*16+hi*8+..7][e=et*32+l31]
// Weights: FRAGMENT-MAJOR: Wf[(fb*4+ks)*512 + lane*8 + e'] =
//          W[fb*16+(lane&15)][ks*32+(lane>>4)*8+e']  (1KB linear per frag)
// ---------------------------------------------------------------------------

// Kernel 0: f32 weights -> bf16 fragment-major (3 x 32KB).
__global__ __launch_bounds__(256) void prep_k(
    const float* __restrict__ Wq, const float* __restrict__ Wk,
    const float* __restrict__ Wv,
    unsigned short* __restrict__ Wqf, unsigned short* __restrict__ Wkf,
    unsigned short* __restrict__ Wvf) {
  int i = blockIdx.x * 256 + threadIdx.x;          // 0..12287
  const float* srcs[3] = {Wq, Wk, Wv};
  unsigned short* dsts[3] = {Wqf, Wkf, Wvf};
  int m = i >> 12, j = i & 4095;                   // j indexes 4-short chunks
  int group = j >> 7;                              // fb*4+ks
  int l     = (j >> 1) & 63;                       // lane
  int e0    = (j & 1) * 4;
  int fb = group >> 2, ks = group & 3;
  int r  = fb * 16 + (l & 15);
  int c  = ks * 32 + (l >> 4) * 8 + e0;
  float4 v = *(const float4*)(srcs[m] + r * NE + c);
  ushort4v o;
  o[0] = f2bf(v.x); o[1] = f2bf(v.y); o[2] = f2bf(v.z); o[3] = f2bf(v.w);
  *(ushort4v*)(dsts[m] + (size_t)j * 4) = o;
}

// wtile with fragment-major weights: one linear 1KB burst per (fb,ks).
static __device__ __forceinline__ f32x4 wtile(const short8 xa[4],
                                              const unsigned short* __restrict__ Wf,
                                              int fb, int lane) {
  f32x4 acc = {0.f, 0.f, 0.f, 0.f};
  #pragma unroll
  for (int ks = 0; ks < 4; ++ks) {
    short8 wf = *(const short8*)(Wf + ((fb * 4 + ks) << 9) + lane * 8);
    acc = __builtin_amdgcn_mfma_f32_16x16x32_bf16(xa[ks], wf, acc, 0, 0, 0);
  }
  return acc;
}

// ---------------------------------------------------------------------------
// Kernel 1: fused QKV projection. 512 blocks, 4 fb per block (X loaded once
// per tile). Fragment-major weight loads (linear 1KB). Q/K routed through
// per-wave 2KB LDS tiles -> all global stores are coalesced 16B bursts.
// ---------------------------------------------------------------------------
__global__ __launch_bounds__(256, 4) void qkv_proj_k(
    const float* __restrict__ X,
    const unsigned short* __restrict__ Wqf, const float* __restrict__ bq,
    const unsigned short* __restrict__ Wkf, const float* __restrict__ bk,
    const unsigned short* __restrict__ Wvf, const float* __restrict__ bv,
    unsigned short* __restrict__ Qs, unsigned short* __restrict__ Kd,
    unsigned short* __restrict__ VT) {
  __shared__ __align__(16) unsigned short qt[4][1024];   // per-wave 2KB tiles
  __shared__ __align__(16) unsigned short kt[4][1024];

  const int lane = threadIdx.x & 63;
  const int wv   = threadIdx.x >> 6;
  const int tile = (blockIdx.x >> 1) * 4 + wv;   // 0..1023
  const int fb0  = (blockIdx.x & 1) * 4;         // output half (4 fb)
  const int m0   = tile * 16;
  const int g    = lane >> 4, li = lane & 15;

  short8 xa[4];
  #pragma unroll
  for (int ks = 0; ks < 4; ++ks) {
    const float* xp = X + (size_t)(m0 + li) * NE + ks * 32 + g * 8;
    float4 x0 = *(const float4*)xp;
    float4 x1 = *(const float4*)(xp + 4);
    short8 t;
    t[0] = (short)f2bf(x0.x); t[1] = (short)f2bf(x0.y);
    t[2] = (short)f2bf(x0.z); t[3] = (short)f2bf(x0.w);
    t[4] = (short)f2bf(x1.x); t[5] = (short)f2bf(x1.y);
    t[6] = (short)f2bf(x1.z); t[7] = (short)f2bf(x1.w);
    xa[ks] = t;
  }

  const int bb  = m0 >> 12;              // batch
  const int tT  = (m0 & 4095) >> 6;      // 64-key tile within batch
  const int jtT = (m0 >> 4) & 3;         // 16-key subtile (= sp)
  const size_t tgbase = ((size_t)(bb * 64 + tT)) * 16;   // group base (x512)

  #pragma unroll
  for (int f2 = 0; f2 < 4; ++f2) {
    const int fb = fb0 + f2;
    // ---- Q -> LDS tile, row-major [j 16][e' 64] ----
    f32x4 aq = wtile(xa, Wqf, fb, lane);
    float biq = bq[fb * 16 + li];
    #pragma unroll
    for (int r = 0; r < 4; ++r)
      qt[wv][(g * 4 + r) * 64 + f2 * 16 + li] = f2bf((aq[r] + biq) * ALPHA);
    // ---- K -> LDS tile, staged-group layout [h 2][gg 4][j 16][e'%8 8] ----
    f32x4 ak = wtile(xa, Wkf, fb, lane);
    float bik = bk[fb * 16 + li];
    const int hk  = f2 >> 1;                 // group-pair index
    const int ggk = (fb & 1) * 2 + (li >> 3);
    #pragma unroll
    for (int r = 0; r < 4; ++r)
      kt[wv][hk * 512 + ggk * 128 + (g * 4 + r) * 8 + (li & 7)] = f2bf(ak[r] + bik);
    // ---- V staged direct (coalesced within the 1KB group) ----
    f32x4 av = wtile(xa, Wvf, fb, lane);
    float biv = bv[fb * 16 + li];
    ushort4v pv;
    #pragma unroll
    for (int r = 0; r < 4; ++r) pv[r] = f2bf(av[r] + biv);
    *(ushort4v*)(VT + (tgbase + jtT * 4 + (fb >> 1)) * 512 +
                 ((g >> 1) * 32 + (fb & 1) * 16 + li) * 8 + (g & 1) * 4) = pv;
  }

  // ---- read back linear, store coalesced 16B (2 per lane each) ----
  #pragma unroll
  for (int r2 = 0; r2 < 2; ++r2) {
    short8 qv = *(const short8*)&qt[wv][lane * 16 + r2 * 8];
    *(short8*)(Qs + (size_t)(m0 + (lane >> 2)) * NE + fb0 * 16 +
               (lane & 3) * 16 + r2 * 8) = qv;
    short8 kv = *(const short8*)&kt[wv][r2 * 512 + lane * 8];
    *(short8*)(Kd + (tgbase + jtT * 4 + (fb0 >> 1) + r2) * 512 + lane * 8) = kv;
  }
}

// ---------------------------------------------------------------------------
// Kernel 2: flash attention — BYTE-IDENTICAL to the round-14/17/18/19
// passing source. 256 blocks x 512 threads, 8 waves/CU. Block = 64 q-rows
// x 4 key-splits. Reg-double-buffered asm global loads, counted vmcnt(8),
// defer-max. (Occupancy is structurally capped at 2 waves/SIMD: the live
// set is ~192 unified regs and the asm "=v" outputs cannot spill — the
// (…,4) variants abort at launch; measured twice, r20/r21.)
// ---------------------------------------------------------------------------
__global__ __launch_bounds__(512, 2) void attn_k(
    const unsigned short* __restrict__ Qs, const unsigned short* __restrict__ Kd,
    const unsigned short* __restrict__ VT, float* __restrict__ Out) {
  __shared__ float smO[2 * SPLITS * 4 * 64 * 16];   // 128 KB
  __shared__ float smML[2 * SPLITS * 64];           // 2 KB

  const int lane = threadIdx.x & 63;
  const int wv   = threadIdx.x >> 6;             // 0..7
  const int qg   = wv >> 2;                      // q-group (0..1)
  const int sp   = wv & 3;                       // key split (0..3)
  const int bi   = blockIdx.x;                   // 0..255
  const int b    = (bi >> 1) & 3;                // batch tied to XCD pair
  const int within = ((bi >> 3) << 1) | (bi & 1);     // 0..63
  const int qb   = within * 64 + qg * 32;        // q-row base for this wave
  const int g    = lane >> 4, li = lane & 15;
  const int l31  = lane & 31, hi = lane >> 5;
  const bool qsel = (lane >> 4) & 1;

  // ---- Q B-frags via asm loads ----
  int4v q00, q01, q02, q03, q10, q11, q12, q13;
  {
    const unsigned short* q0 = Qs + (size_t)(b * NS + qb + li) * NE + g * 8;
    const unsigned short* q1 = Qs + (size_t)(b * NS + qb + 16 + li) * NE + g * 8;
    unsigned long long a0 = (unsigned long long)q0, a1 = (unsigned long long)q1;
    asm volatile("global_load_dwordx4 %0, %1, off"             : "=v"(q00) : "v"(a0));
    asm volatile("global_load_dwordx4 %0, %1, off offset:64"   : "=v"(q01) : "v"(a0));
    asm volatile("global_load_dwordx4 %0, %1, off offset:128"  : "=v"(q02) : "v"(a0));
    asm volatile("global_load_dwordx4 %0, %1, off offset:192"  : "=v"(q03) : "v"(a0));
    asm volatile("global_load_dwordx4 %0, %1, off"             : "=v"(q10) : "v"(a1));
    asm volatile("global_load_dwordx4 %0, %1, off offset:64"   : "=v"(q11) : "v"(a1));
    asm volatile("global_load_dwordx4 %0, %1, off offset:128"  : "=v"(q12) : "v"(a1));
    asm volatile("global_load_dwordx4 %0, %1, off offset:192"  : "=v"(q13) : "v"(a1));
  }

  const size_t stbase = (size_t)b * 64 * 16 * 512;       // shorts
  const int    kvoff  = sp * 2048 + lane * 8;            // shorts
  const unsigned long long kbase =
      (unsigned long long)(Kd + stbase + kvoff);
  const unsigned long long vbase =
      (unsigned long long)(VT + stbase + kvoff);

  int4v ka0, ka1, ka2, ka3, va0, va1, va2, va3;
  int4v kb0, kb1, kb2, kb3, vb0, vb1, vb2, vb3;

  #define LOAD_SET(K0,K1,K2,K3,V0,V1,V2,V3,T)                                   \
    {                                                                           \
      unsigned long long ka_ = kbase + (unsigned long long)(T) * 16384;         \
      unsigned long long va_ = vbase + (unsigned long long)(T) * 16384;         \
      asm volatile("global_load_dwordx4 %0, %1, off"             : "=v"(K0) : "v"(ka_)); \
      asm volatile("global_load_dwordx4 %0, %1, off offset:1024" : "=v"(K1) : "v"(ka_)); \
      asm volatile("global_load_dwordx4 %0, %1, off offset:2048" : "=v"(K2) : "v"(ka_)); \
      asm volatile("global_load_dwordx4 %0, %1, off offset:3072" : "=v"(K3) : "v"(ka_)); \
      asm volatile("global_load_dwordx4 %0, %1, off"             : "=v"(V0) : "v"(va_)); \
      asm volatile("global_load_dwordx4 %0, %1, off offset:1024" : "=v"(V1) : "v"(va_)); \
      asm volatile("global_load_dwordx4 %0, %1, off offset:2048" : "=v"(V2) : "v"(va_)); \
      asm volatile("global_load_dwordx4 %0, %1, off offset:3072" : "=v"(V3) : "v"(va_)); \
    }
  #define LOAD_A(T) LOAD_SET(ka0,ka1,ka2,ka3,va0,va1,va2,va3,T)
  #define LOAD_B(T) LOAD_SET(kb0,kb1,kb2,kb3,vb0,vb1,vb2,vb3,T)
  #define WAIT8 asm volatile("s_waitcnt vmcnt(8)" ::: "memory"); \
                __builtin_amdgcn_sched_barrier(0);

  f32x16 o[4];
  #pragma unroll
  for (int et = 0; et < 4; ++et)
    #pragma unroll
    for (int r = 0; r < 16; ++r) o[et][r] = 0.f;
  float m0 = -1e30f, m1 = -1e30f, L0 = 0.f, L1 = 0.f;

  const int src01 = (lane & 15) | (lane & 32);
  const int src23 = src01 + 16;

  #define BODY(K0,K1,K2,K3,V0,V1,V2,V3)                                        \
  {                                                                            \
    f32x4 s0 = {0.f, 0.f, 0.f, 0.f}, s1 = {0.f, 0.f, 0.f, 0.f};                \
    __builtin_amdgcn_s_setprio(1);                                             \
    s0 = __builtin_amdgcn_mfma_f32_16x16x32_bf16(as_s8(K0), as_s8(q00), s0, 0,0,0); \
    s1 = __builtin_amdgcn_mfma_f32_16x16x32_bf16(as_s8(K0), as_s8(q10), s1, 0,0,0); \
    s0 = __builtin_amdgcn_mfma_f32_16x16x32_bf16(as_s8(K1), as_s8(q01), s0, 0,0,0); \
    s1 = __builtin_amdgcn_mfma_f32_16x16x32_bf16(as_s8(K1), as_s8(q11), s1, 0,0,0); \
    s0 = __builtin_amdgcn_mfma_f32_16x16x32_bf16(as_s8(K2), as_s8(q02), s0, 0,0,0); \
    s1 = __builtin_amdgcn_mfma_f32_16x16x32_bf16(as_s8(K2), as_s8(q12), s1, 0,0,0); \
    s0 = __builtin_amdgcn_mfma_f32_16x16x32_bf16(as_s8(K3), as_s8(q03), s0, 0,0,0); \
    s1 = __builtin_amdgcn_mfma_f32_16x16x32_bf16(as_s8(K3), as_s8(q13), s1, 0,0,0); \
    __builtin_amdgcn_s_setprio(0);                                             \
    float tm0 = fmaxf(fmaxf(s0[0], s0[1]), fmaxf(s0[2], s0[3]));               \
    float tm1 = fmaxf(fmaxf(s1[0], s1[1]), fmaxf(s1[2], s1[3]));               \
    if (__any(fmaxf(tm0 - m0, tm1 - m1) > DEFER_THR)) {                        \
      tm0 = fmaxf(tm0, __shfl_xor(tm0, 16));                                   \
      tm1 = fmaxf(tm1, __shfl_xor(tm1, 16));                                   \
      tm0 = fmaxf(tm0, __shfl_xor(tm0, 32));                                   \
      tm1 = fmaxf(tm1, __shfl_xor(tm1, 32));                                   \
      float mn0 = fmaxf(m0, tm0), c0 = __builtin_amdgcn_exp2f(m0 - mn0);       \
      float mn1 = fmaxf(m1, tm1), c1 = __builtin_amdgcn_exp2f(m1 - mn1);       \
      const float cmy = qsel ? c1 : c0;                                        \
      o[0] = o[0] * cmy; o[1] = o[1] * cmy;                                    \
      o[2] = o[2] * cmy; o[3] = o[3] * cmy;                                    \
      L0 *= c0; L1 *= c1; m0 = mn0; m1 = mn1;                                  \
    }                                                                          \
    float p00 = __builtin_amdgcn_exp2f(s0[0] - m0);                            \
    float p01 = __builtin_amdgcn_exp2f(s0[1] - m0);                            \
    float p02 = __builtin_amdgcn_exp2f(s0[2] - m0);                            \
    float p03 = __builtin_amdgcn_exp2f(s0[3] - m0);                            \
    float p10 = __builtin_amdgcn_exp2f(s1[0] - m1);                            \
    float p11 = __builtin_amdgcn_exp2f(s1[1] - m1);                            \
    float p12 = __builtin_amdgcn_exp2f(s1[2] - m1);                            \
    float p13 = __builtin_amdgcn_exp2f(s1[3] - m1);                            \
    L0 += (p00 + p01) + (p02 + p03);                                           \
    L1 += (p10 + p11) + (p12 + p13);                                           \
    unsigned int pk00 = pack2bf(p00, p01);                                     \
    unsigned int pk01 = pack2bf(p02, p03);                                     \
    unsigned int pk10 = pack2bf(p10, p11);                                     \
    unsigned int pk11 = pack2bf(p12, p13);                                     \
    int ta, tb, w0, w1, w2, w3;                                                \
    ta = __shfl((int)pk00, src01); tb = __shfl((int)pk10, src01);              \
    w0 = qsel ? tb : ta;                                                       \
    ta = __shfl((int)pk01, src01); tb = __shfl((int)pk11, src01);              \
    w1 = qsel ? tb : ta;                                                       \
    ta = __shfl((int)pk00, src23); tb = __shfl((int)pk10, src23);              \
    w2 = qsel ? tb : ta;                                                       \
    ta = __shfl((int)pk01, src23); tb = __shfl((int)pk11, src23);              \
    w3 = qsel ? tb : ta;                                                       \
    union { int4v i4; short8 s8; } pb;                                         \
    pb.i4 = (int4v){w0, w1, w2, w3};                                           \
    __builtin_amdgcn_s_setprio(1);                                             \
    o[0] = __builtin_amdgcn_mfma_f32_32x32x16_bf16(as_s8(V0), pb.s8, o[0], 0,0,0); \
    o[1] = __builtin_amdgcn_mfma_f32_32x32x16_bf16(as_s8(V1), pb.s8, o[1], 0,0,0); \
    o[2] = __builtin_amdgcn_mfma_f32_32x32x16_bf16(as_s8(V2), pb.s8, o[2], 0,0,0); \
    o[3] = __builtin_amdgcn_mfma_f32_32x32x16_bf16(as_s8(V3), pb.s8, o[3], 0,0,0); \
    __builtin_amdgcn_s_setprio(0);                                             \
  }

  LOAD_A(0);
  WAIT8;   // Q frags ready; tile 0 in flight

  #pragma unroll 1
  for (int t2 = 0; t2 < NIT; t2 += 2) {
    LOAD_B(t2 + 1);
    WAIT8;
    BODY(ka0, ka1, ka2, ka3, va0, va1, va2, va3)
    LOAD_A((t2 + 2) & (NIT - 1));
    WAIT8;
    BODY(kb0, kb1, kb2, kb3, vb0, vb1, vb2, vb3)
  }

  __syncthreads();

  // ---- epilogue: publish split partials ([qg][sp][et][lane][16]) ----
  L0 += __shfl_xor(L0, 16); L0 += __shfl_xor(L0, 32);
  L1 += __shfl_xor(L1, 16); L1 += __shfl_xor(L1, 32);
  #pragma unroll
  for (int et = 0; et < 4; ++et)
    #pragma unroll
    for (int rq = 0; rq < 4; ++rq) {
      float4 v;
      v.x = o[et][rq * 4 + 0]; v.y = o[et][rq * 4 + 1];
      v.z = o[et][rq * 4 + 2]; v.w = o[et][rq * 4 + 3];
      *(float4*)(smO + (size_t)(((qg * SPLITS + sp) * 4 + et) * 64 + lane) * 16 + rq * 4) = v;
    }
  if (lane < 16) {
    smML[(qg * SPLITS + sp) * 64 + lane]      = m0;
    smML[(qg * SPLITS + sp) * 64 + 16 + lane] = m1;
    smML[(qg * SPLITS + sp) * 64 + 32 + lane] = L0;
    smML[(qg * SPLITS + sp) * 64 + 48 + lane] = L1;
  }
  __syncthreads();

  // ---- combine: wave wv handles (q-group wv>>2, e-block wv&3) ----
  const int cqg = wv >> 2, cet = wv & 3;
  float ms[SPLITS], Ls[SPLITS];
  #pragma unroll
  for (int sp2 = 0; sp2 < SPLITS; ++sp2) {
    ms[sp2] = smML[(cqg * SPLITS + sp2) * 64 + l31];
    Ls[sp2] = smML[(cqg * SPLITS + sp2) * 64 + 32 + l31];
  }
  float M = fmaxf(fmaxf(ms[0], ms[1]), fmaxf(ms[2], ms[3]));
  float W[SPLITS], Ltot = 0.f;
  #pragma unroll
  for (int sp2 = 0; sp2 < SPLITS; ++sp2) {
    W[sp2] = __builtin_amdgcn_exp2f(ms[sp2] - M);
    Ltot += W[sp2] * Ls[sp2];
  }
  const float rL = 1.f / Ltot;
  float* Orow = Out + (size_t)(b * NS + within * 64 + cqg * 32 + l31) * NE + cet * 32;
  #pragma unroll
  for (int rq = 0; rq < 4; ++rq) {
    float4 acc = make_float4(0.f, 0.f, 0.f, 0.f);
    #pragma unroll
    for (int sp2 = 0; sp2 < SPLITS; ++sp2) {
      float4 v = *(const float4*)(smO +
          (size_t)(((cqg * SPLITS + sp2) * 4 + cet) * 64 + lane) * 16 + rq * 4);
      acc.x += W[sp2] * v.x; acc.y += W[sp2] * v.y;
      acc.z += W[sp2] * v.z; acc.w += W[sp2] * v.w;
    }
    acc.x *= rL; acc.y *= rL; acc.z *= rL; acc.w *= rL;
    *(float4*)(Orow + 8 * rq + 4 * hi) = acc;
  }
}

extern "C" void kernel_launch(void* const* d_in, const int* in_sizes, int n_in,
                              void* d_out, int out_size, void* d_ws, size_t ws_size,
                              hipStream_t stream) {
  const float* X  = (const float*)d_in[0];
  // d_in[1] = context : unused (per-row bias is softmax-invariant)
  const float* Wq = (const float*)d_in[2];
  const float* bq = (const float*)d_in[3];
  const float* Wk = (const float*)d_in[4];
  const float* bk = (const float*)d_in[5];
  const float* Wv = (const float*)d_in[6];
  const float* bv = (const float*)d_in[7];
  // d_in[8] = Wc, d_in[9] = bc : unused

  unsigned short* Qs  = (unsigned short*)d_ws;                // 4 MB
  unsigned short* Kd  = Qs + (size_t)NB * NS * NE;            // 4 MB (staged)
  unsigned short* VT  = Kd + (size_t)NB * NS * NE;            // 4 MB (staged)
  unsigned short* Wqf = VT + (size_t)NB * NS * NE;            // 32 KB x3 (frag-major)
  unsigned short* Wkf = Wqf + NE * NE;
  unsigned short* Wvf = Wkf + NE * NE;

  prep_k<<<48, 256, 0, stream>>>(Wq, Wk, Wv, Wqf, Wkf, Wvf);
  qkv_proj_k<<<512, 256, 0, stream>>>(X, Wqf, bq, Wkf, bk, Wvf, bv, Qs, Kd, VT);
  attn_k<<<256, 512, 0, stream>>>(Qs, Kd, VT, (float*)d_out);
}